// Round 1
// baseline (292.386 us; speedup 1.0000x reference)
//
#include <hip/hip_runtime.h>
#include <math.h>

#define D 64
#define EPS 1e-6f
#define SLOPE 0.2f
#define NPW 4   // nodes per wave in node_kernel

__device__ __forceinline__ float wave_sum(float v) {
#pragma unroll
  for (int m = 32; m > 0; m >>= 1) v += __shfl_xor(v, m, 64);
  return v;
}
__device__ __forceinline__ float wave_max(float v) {
#pragma unroll
  for (int m = 32; m > 0; m >>= 1) v = fmaxf(v, __shfl_xor(v, m, 64));
  return v;
}
// broadcast lane k's value to all lanes via v_readlane (k is wave-uniform)
__device__ __forceinline__ float bcast(float v, int k) {
  return __int_as_float(__builtin_amdgcn_readlane(__float_as_int(v), k));
}

// ---------------------------------------------------------------------------
// Kernel A: per-node fused  LN1 -> dense = x@Ww+Wb, at1 = q@W1w+W1b,
// at2 = x@W2w+W2b, s1 = tanh(<at1,q>), s2 = tanh(<at2,x>)
// wave-per-node (lane = feature), NPW nodes per wave per k-loop to amortize
// the LDS W reads.  W layout k-major: lane d reads W[k*64+d] -> 2-way bank
// aliasing only (free).
// ---------------------------------------------------------------------------
__global__ __launch_bounds__(256) void node_kernel(
    const float* __restrict__ query, const float* __restrict__ input_,
    const float* __restrict__ Ww,  const float* __restrict__ Wb,
    const float* __restrict__ W1w, const float* __restrict__ W1b,
    const float* __restrict__ W2w, const float* __restrict__ W2b,
    const float* __restrict__ g1,  const float* __restrict__ b1,
    float* __restrict__ dense, float* __restrict__ s1, float* __restrict__ s2,
    int N)
{
  __shared__ float sW0[D * D];
  __shared__ float sW1[D * D];
  __shared__ float sW2[D * D];
  __shared__ float sWb[D], sW1b[D], sW2b[D], sg1[D], sb1[D];

  for (int idx = threadIdx.x; idx < D * D; idx += blockDim.x) {
    sW0[idx] = Ww[idx];
    sW1[idx] = W1w[idx];
    sW2[idx] = W2w[idx];
  }
  if (threadIdx.x < D) {
    sWb[threadIdx.x]  = Wb[threadIdx.x];
    sW1b[threadIdx.x] = W1b[threadIdx.x];
    sW2b[threadIdx.x] = W2b[threadIdx.x];
    sg1[threadIdx.x]  = g1[threadIdx.x];
    sb1[threadIdx.x]  = b1[threadIdx.x];
  }
  __syncthreads();

  const int lane  = threadIdx.x & 63;
  const int wave  = blockIdx.x * (blockDim.x >> 6) + (threadIdx.x >> 6);
  const int nwave = gridDim.x * (blockDim.x >> 6);

  for (int base = wave * NPW; base < N; base += nwave * NPW) {
    float x[NPW], q[NPW];
#pragma unroll
    for (int n = 0; n < NPW; ++n) {
      int i = base + n;
      float v = 0.f, qq = 0.f;
      if (i < N) {
        v  = input_[(size_t)i * D + lane];
        qq = query[(size_t)i * D + lane];
      }
      float mu  = wave_sum(v) * (1.f / D);
      float dv  = v - mu;
      float var = wave_sum(dv * dv) * (1.f / D);
      x[n] = dv * rsqrtf(var + EPS) * sg1[lane] + sb1[lane];
      q[n] = qq;
    }

    float aD[NPW], a1[NPW], a2[NPW];
#pragma unroll
    for (int n = 0; n < NPW; ++n) { aD[n] = 0.f; a1[n] = 0.f; a2[n] = 0.f; }

#pragma unroll 4
    for (int k = 0; k < D; ++k) {
      float w0 = sW0[k * D + lane];
      float w1 = sW1[k * D + lane];
      float w2 = sW2[k * D + lane];
#pragma unroll
      for (int n = 0; n < NPW; ++n) {
        float xk = bcast(x[n], k);
        float qk = bcast(q[n], k);
        aD[n] = fmaf(xk, w0, aD[n]);
        a1[n] = fmaf(qk, w1, a1[n]);
        a2[n] = fmaf(xk, w2, a2[n]);
      }
    }

#pragma unroll
    for (int n = 0; n < NPW; ++n) {
      int i = base + n;
      if (i < N) {
        dense[(size_t)i * D + lane] = aD[n] + sWb[lane];
        float t1 = wave_sum((a1[n] + sW1b[lane]) * q[n]);
        float t2 = wave_sum((a2[n] + sW2b[lane]) * x[n]);
        if (lane == 0) {
          s1[i] = tanhf(t1);
          s2[i] = tanhf(t2);
        }
      }
    }
  }
}

// ---------------------------------------------------------------------------
// Kernel B: CSR row pointers from the sorted edge_row array.
// row_ptr[r] = first e with edge_row[e] >= r;  row_ptr[N] = E.
// ---------------------------------------------------------------------------
__global__ void rowptr_kernel(const int* __restrict__ erow,
                              int* __restrict__ row_ptr, int E, int N)
{
  int e = blockIdx.x * blockDim.x + threadIdx.x;
  if (e >= E) return;
  int r = erow[e];
  if (e == 0) {
    for (int rr = 0; rr <= r; ++rr) row_ptr[rr] = 0;
  } else {
    int rp = erow[e - 1];
    for (int rr = rp + 1; rr <= r; ++rr) row_ptr[rr] = e;
  }
  if (e == E - 1) {
    for (int rr = r + 1; rr <= N; ++rr) row_ptr[rr] = E;
  }
}

// ---------------------------------------------------------------------------
// Kernel C: per-row  leaky_relu(s1[i]+s2[j]) -> softmax over row ->
// out[i] = sum attn * dense[j] -> LN2.   wave-per-row, lane = feature.
// Pass 1: lanes split edges for the max.  Pass 2: serial edges, all lanes
// redundantly compute the scalar weight, lane d accumulates feature d.
// ---------------------------------------------------------------------------
__global__ __launch_bounds__(256) void edge_kernel(
    const int* __restrict__ row_ptr, const int* __restrict__ ecol,
    const float* __restrict__ s1, const float* __restrict__ s2,
    const float* __restrict__ dense,
    const float* __restrict__ g2, const float* __restrict__ b2,
    float* __restrict__ out, int N)
{
  const int lane = threadIdx.x & 63;
  const int row  = blockIdx.x * (blockDim.x >> 6) + (threadIdx.x >> 6);
  if (row >= N) return;

  const int start = row_ptr[row];
  const int end   = row_ptr[row + 1];
  const float s1i = s1[row];

  // pass 1: row max of leaky_relu(s1[i] + s2[j])
  float m = -INFINITY;
  for (int e = start + lane; e < end; e += 64) {
    float l = s1i + s2[ecol[e]];
    l = (l > 0.f) ? l : SLOPE * l;
    m = fmaxf(m, l);
  }
  m = wave_max(m);

  // pass 2: exp-weights + weighted accumulation of dense rows
  float acc = 0.f, denom = 0.f;
  for (int e = start; e < end; ++e) {
    int c = ecol[e];
    float l = s1i + s2[c];
    l = (l > 0.f) ? l : SLOPE * l;
    float w = __expf(l - m);
    denom += w;
    acc = fmaf(w, dense[(size_t)c * D + lane], acc);
  }
  float o = (end > start) ? (acc / denom) : 0.f;

  // LN2
  float mu  = wave_sum(o) * (1.f / D);
  float dv  = o - mu;
  float var = wave_sum(dv * dv) * (1.f / D);
  out[(size_t)row * D + lane] = dv * rsqrtf(var + EPS) * g2[lane] + b2[lane];
}

// ---------------------------------------------------------------------------
extern "C" void kernel_launch(void* const* d_in, const int* in_sizes, int n_in,
                              void* d_out, int out_size, void* d_ws, size_t ws_size,
                              hipStream_t stream)
{
  const float* query  = (const float*)d_in[0];
  const float* input_ = (const float*)d_in[1];
  const int*   erow   = (const int*)d_in[2];
  const int*   ecol   = (const int*)d_in[3];
  const float* Ww     = (const float*)d_in[4];
  const float* Wb     = (const float*)d_in[5];
  const float* W1w    = (const float*)d_in[6];
  const float* W1b    = (const float*)d_in[7];
  const float* W2w    = (const float*)d_in[8];
  const float* W2b    = (const float*)d_in[9];
  const float* g1     = (const float*)d_in[10];
  const float* b1     = (const float*)d_in[11];
  const float* g2     = (const float*)d_in[12];
  const float* b2     = (const float*)d_in[13];

  const int N = in_sizes[0] / D;
  const int E = in_sizes[2];
  float* out = (float*)d_out;

  // workspace layout: dense [N*D] f32 | s1 [N] | s2 [N] | row_ptr [N+1] int
  char* ws = (char*)d_ws;
  float* dense   = (float*)ws;
  float* s1      = dense + (size_t)N * D;
  float* s2      = s1 + N;
  int*   row_ptr = (int*)(s2 + N);

  node_kernel<<<1024, 256, 0, stream>>>(query, input_, Ww, Wb, W1w, W1b,
                                        W2w, W2b, g1, b1, dense, s1, s2, N);
  rowptr_kernel<<<(E + 255) / 256, 256, 0, stream>>>(erow, row_ptr, E, N);
  edge_kernel<<<(N + 3) / 4, 256, 0, stream>>>(row_ptr, ecol, s1, s2, dense,
                                               g2, b2, out, N);
}

// Round 2
// 246.163 us; speedup vs baseline: 1.1878x; 1.1878x over previous
//
#include <hip/hip_runtime.h>
#include <math.h>

#define D 64
#define EPS 1e-6f
#define SLOPE 0.2f
#define NPW 8   // nodes per wave in node_kernel

__device__ __forceinline__ float wave_sum(float v) {
#pragma unroll
  for (int m = 32; m > 0; m >>= 1) v += __shfl_xor(v, m, 64);
  return v;
}
__device__ __forceinline__ float wave_max(float v) {
#pragma unroll
  for (int m = 32; m > 0; m >>= 1) v = fmaxf(v, __shfl_xor(v, m, 64));
  return v;
}
// broadcast lane k's value to all lanes (k wave-uniform -> v_readlane)
__device__ __forceinline__ float bcast(float v, int k) {
  return __int_as_float(__builtin_amdgcn_readlane(__float_as_int(v), k));
}
__device__ __forceinline__ int bcast_i(int v, int k) {
  return __builtin_amdgcn_readlane(v, k);
}
__device__ __forceinline__ float leaky(float l) {
  return (l > 0.f) ? l : SLOPE * l;
}

// ---------------------------------------------------------------------------
// Kernel A: per-node fused  LN1 -> dense = x@Ww+Wb, at1 = q@W1w+W1b,
// at2 = x@W2w+W2b, s1 = tanh(<at1,q>), s2 = tanh(<at2,x>)
// wave-per-node (lane = feature), NPW nodes per wave per k-loop to amortize
// the LDS W reads.
// ---------------------------------------------------------------------------
__global__ __launch_bounds__(256) void node_kernel(
    const float* __restrict__ query, const float* __restrict__ input_,
    const float* __restrict__ Ww,  const float* __restrict__ Wb,
    const float* __restrict__ W1w, const float* __restrict__ W1b,
    const float* __restrict__ W2w, const float* __restrict__ W2b,
    const float* __restrict__ g1,  const float* __restrict__ b1,
    float* __restrict__ dense, float* __restrict__ s1, float* __restrict__ s2,
    int N)
{
  __shared__ float sW0[D * D];
  __shared__ float sW1[D * D];
  __shared__ float sW2[D * D];
  __shared__ float sWb[D], sW1b[D], sW2b[D], sg1[D], sb1[D];

  for (int idx = threadIdx.x; idx < D * D; idx += blockDim.x) {
    sW0[idx] = Ww[idx];
    sW1[idx] = W1w[idx];
    sW2[idx] = W2w[idx];
  }
  if (threadIdx.x < D) {
    sWb[threadIdx.x]  = Wb[threadIdx.x];
    sW1b[threadIdx.x] = W1b[threadIdx.x];
    sW2b[threadIdx.x] = W2b[threadIdx.x];
    sg1[threadIdx.x]  = g1[threadIdx.x];
    sb1[threadIdx.x]  = b1[threadIdx.x];
  }
  __syncthreads();

  const int lane  = threadIdx.x & 63;
  const int wave  = blockIdx.x * (blockDim.x >> 6) + (threadIdx.x >> 6);
  const int nwave = gridDim.x * (blockDim.x >> 6);

  for (int base = wave * NPW; base < N; base += nwave * NPW) {
    float x[NPW], q[NPW];
#pragma unroll
    for (int n = 0; n < NPW; ++n) {
      int i = base + n;
      float v = 0.f, qq = 0.f;
      if (i < N) {
        v  = input_[(size_t)i * D + lane];
        qq = query[(size_t)i * D + lane];
      }
      float mu  = wave_sum(v) * (1.f / D);
      float dv  = v - mu;
      float var = wave_sum(dv * dv) * (1.f / D);
      x[n] = dv * rsqrtf(var + EPS) * sg1[lane] + sb1[lane];
      q[n] = qq;
    }

    float aD[NPW], a1[NPW], a2[NPW];
#pragma unroll
    for (int n = 0; n < NPW; ++n) { aD[n] = 0.f; a1[n] = 0.f; a2[n] = 0.f; }

#pragma unroll 4
    for (int k = 0; k < D; ++k) {
      float w0 = sW0[k * D + lane];
      float w1 = sW1[k * D + lane];
      float w2 = sW2[k * D + lane];
#pragma unroll
      for (int n = 0; n < NPW; ++n) {
        float xk = bcast(x[n], k);
        float qk = bcast(q[n], k);
        aD[n] = fmaf(xk, w0, aD[n]);
        a1[n] = fmaf(qk, w1, a1[n]);
        a2[n] = fmaf(xk, w2, a2[n]);
      }
    }

#pragma unroll
    for (int n = 0; n < NPW; ++n) {
      int i = base + n;
      if (i < N) {
        dense[(size_t)i * D + lane] = aD[n] + sWb[lane];
        float t1 = wave_sum((a1[n] + sW1b[lane]) * q[n]);
        float t2 = wave_sum((a2[n] + sW2b[lane]) * x[n]);
        if (lane == 0) s1[i] = tanhf(t1);
        if (lane == 1) s2[i] = tanhf(t2);
      }
    }
  }
}

// ---------------------------------------------------------------------------
// Kernel B: CSR row pointers from the sorted edge_row array.
// ---------------------------------------------------------------------------
__global__ void rowptr_kernel(const int* __restrict__ erow,
                              int* __restrict__ row_ptr, int E, int N)
{
  int e = blockIdx.x * blockDim.x + threadIdx.x;
  if (e >= E) return;
  int r = erow[e];
  if (e == 0) {
    for (int rr = 0; rr <= r; ++rr) row_ptr[rr] = 0;
  } else {
    int rp = erow[e - 1];
    for (int rr = rp + 1; rr <= r; ++rr) row_ptr[rr] = e;
  }
  if (e == E - 1) {
    for (int rr = r + 1; rr <= N; ++rr) row_ptr[rr] = E;
  }
}

// ---------------------------------------------------------------------------
// Kernel C: per-row softmax + SpMM + LN2, wave-per-row, lane = feature.
// Fast path (deg <= 64): one lane per edge computes its logit/weight in
// parallel; the accumulate loop broadcasts (col, w) via readlane and does one
// coalesced dense-row load per edge (loads independent -> pipelined).
// ---------------------------------------------------------------------------
__global__ __launch_bounds__(256) void edge_kernel(
    const int* __restrict__ row_ptr, const int* __restrict__ ecol,
    const float* __restrict__ s1, const float* __restrict__ s2,
    const float* __restrict__ dense,
    const float* __restrict__ g2, const float* __restrict__ b2,
    float* __restrict__ out, int N)
{
  const int lane = threadIdx.x & 63;
  const int row  = blockIdx.x * (blockDim.x >> 6) + (threadIdx.x >> 6);
  if (row >= N) return;

  const int start = row_ptr[row];
  const int end   = row_ptr[row + 1];
  const int deg   = end - start;
  const float s1i = s1[row];

  float acc = 0.f, denom = 0.f;

  if (deg <= 64) {
    int   c = 0;
    float l = -INFINITY;
    if (lane < deg) {
      c = ecol[start + lane];
      l = leaky(s1i + s2[c]);
    }
    float m = wave_max(l);
    float w = (lane < deg) ? __expf(l - m) : 0.f;
    denom = wave_sum(w);
#pragma unroll 4
    for (int e = 0; e < deg; ++e) {
      int   ce = bcast_i(c, e);
      float we = bcast(w, e);
      acc = fmaf(we, dense[(size_t)ce * D + lane], acc);
    }
  } else {
    float m = -INFINITY;
    for (int e = start + lane; e < end; e += 64)
      m = fmaxf(m, leaky(s1i + s2[ecol[e]]));
    m = wave_max(m);

    float wsum = 0.f;
    for (int b = start; b < end; b += 64) {
      int nb = min(64, end - b);
      int   c = 0;
      float w = 0.f;
      if (lane < nb) {
        c = ecol[b + lane];
        w = __expf(leaky(s1i + s2[c]) - m);
      }
      wsum += w;
#pragma unroll 4
      for (int e = 0; e < nb; ++e) {
        int   ce = bcast_i(c, e);
        float we = bcast(w, e);
        acc = fmaf(we, dense[(size_t)ce * D + lane], acc);
      }
    }
    denom = wave_sum(wsum);
  }

  float o = (deg > 0) ? (acc / denom) : 0.f;

  // LN2
  float mu  = wave_sum(o) * (1.f / D);
  float dv  = o - mu;
  float var = wave_sum(dv * dv) * (1.f / D);
  out[(size_t)row * D + lane] = dv * rsqrtf(var + EPS) * g2[lane] + b2[lane];
}

// ---------------------------------------------------------------------------
extern "C" void kernel_launch(void* const* d_in, const int* in_sizes, int n_in,
                              void* d_out, int out_size, void* d_ws, size_t ws_size,
                              hipStream_t stream)
{
  const float* query  = (const float*)d_in[0];
  const float* input_ = (const float*)d_in[1];
  const int*   erow   = (const int*)d_in[2];
  const int*   ecol   = (const int*)d_in[3];
  const float* Ww     = (const float*)d_in[4];
  const float* Wb     = (const float*)d_in[5];
  const float* W1w    = (const float*)d_in[6];
  const float* W1b    = (const float*)d_in[7];
  const float* W2w    = (const float*)d_in[8];
  const float* W2b    = (const float*)d_in[9];
  const float* g1     = (const float*)d_in[10];
  const float* b1     = (const float*)d_in[11];
  const float* g2     = (const float*)d_in[12];
  const float* b2     = (const float*)d_in[13];

  const int N = in_sizes[0] / D;
  const int E = in_sizes[2];
  float* out = (float*)d_out;

  // workspace layout: dense [N*D] f32 | s1 [N] | s2 [N] | row_ptr [N+1] int
  char* ws = (char*)d_ws;
  float* dense   = (float*)ws;
  float* s1      = dense + (size_t)N * D;
  float* s2      = s1 + N;
  int*   row_ptr = (int*)(s2 + N);

  node_kernel<<<512, 256, 0, stream>>>(query, input_, Ww, Wb, W1w, W1b,
                                       W2w, W2b, g1, b1, dense, s1, s2, N);
  rowptr_kernel<<<(E + 255) / 256, 256, 0, stream>>>(erow, row_ptr, E, N);
  edge_kernel<<<(N + 3) / 4, 256, 0, stream>>>(row_ptr, ecol, s1, s2, dense,
                                               g2, b2, out, N);
}

// Round 3
// 174.069 us; speedup vs baseline: 1.6797x; 1.4142x over previous
//
#include <hip/hip_runtime.h>
#include <math.h>

#define D 64
#define EPS 1e-6f
#define SLOPE 0.2f

typedef _Float16 f16;
typedef _Float16 f16x4 __attribute__((ext_vector_type(4)));
typedef float f32x4 __attribute__((ext_vector_type(4)));

__device__ __forceinline__ float wave_sum(float v) {
#pragma unroll
  for (int m = 32; m > 0; m >>= 1) v += __shfl_xor(v, m, 64);
  return v;
}
__device__ __forceinline__ float wave_max(float v) {
#pragma unroll
  for (int m = 32; m > 0; m >>= 1) v = fmaxf(v, __shfl_xor(v, m, 64));
  return v;
}
// reduce across the 4 lane-groups (lanes differing in bits 4,5) -> all lanes
__device__ __forceinline__ float red4(float v) {
  v += __shfl_xor(v, 16, 64);
  v += __shfl_xor(v, 32, 64);
  return v;
}
__device__ __forceinline__ float bcast(float v, int k) {
  return __int_as_float(__builtin_amdgcn_readlane(__float_as_int(v), k));
}
__device__ __forceinline__ int bcast_i(int v, int k) {
  return __builtin_amdgcn_readlane(v, k);
}
__device__ __forceinline__ float leaky(float l) {
  return (l > 0.f) ? l : SLOPE * l;
}

// ---------------------------------------------------------------------------
// W prep: transpose the three [k][n] f32 weight matrices to n-major f16
// wt[mat*4096 + n*64 + k] so MFMA fragments are contiguous 8B loads.
// ---------------------------------------------------------------------------
__global__ void wprep_kernel(const float* __restrict__ Ww,
                             const float* __restrict__ W1w,
                             const float* __restrict__ W2w,
                             f16* __restrict__ wt)
{
  int i = blockIdx.x * blockDim.x + threadIdx.x;   // 0 .. 3*4096-1
  if (i >= 3 * 4096) return;
  int mat = i >> 12, idx = i & 4095;
  int n = idx >> 6, k = idx & 63;
  const float* src = (mat == 0) ? Ww : (mat == 1) ? W1w : W2w;
  wt[i] = (f16)src[k * 64 + n];
}

// ---------------------------------------------------------------------------
// Node kernel (MFMA): per wave, 16 nodes.
//   LN1 -> xh,qh f16 fragments (lane&15 = node, k = c*16+(lane>>4)*4+j)
//   dense = X @ Ww + Wb          (A = xh, B = wt0 fragment)
//   Y1 = W1^T Q^T, Y2 = W2^T X^T (A = wt fragment, B = qh/xh SAME registers)
//   s1[m] = tanh(sum_d Y1[d,m]*q[m,d] + <W1b,q>)  -- C-row index == A-k index
//   so the dot needs no transpose at all.
// ---------------------------------------------------------------------------
__global__ __launch_bounds__(256) void node_kernel(
    const float* __restrict__ query, const float* __restrict__ input_,
    const f16* __restrict__ wt,
    const float* __restrict__ Wb,  const float* __restrict__ W1b,
    const float* __restrict__ W2b,
    const float* __restrict__ g1,  const float* __restrict__ b1,
    float* __restrict__ dense, float* __restrict__ s1, float* __restrict__ s2,
    int N)
{
  const int lane = threadIdx.x & 63;
  const int grp  = lane >> 4;        // 0..3
  const int mloc = lane & 15;        // node within tile (A/B role)
  const int wv   = threadIdx.x >> 6;
  const int nb   = blockIdx.x * 64 + wv * 16;
  const int m    = nb + mloc;
  const bool mv  = (m < N);

  // ---- natural loads: lane holds features k = c*16 + grp*4 + j ----
  float vq[4][4], vi[4][4];
#pragma unroll
  for (int c = 0; c < 4; ++c) {
    int k0 = c * 16 + grp * 4;
    f32x4 qv = {0.f, 0.f, 0.f, 0.f}, iv = {0.f, 0.f, 0.f, 0.f};
    if (mv) {
      qv = *(const f32x4*)(query  + (size_t)m * D + k0);
      iv = *(const f32x4*)(input_ + (size_t)m * D + k0);
    }
#pragma unroll
    for (int j = 0; j < 4; ++j) { vq[c][j] = qv[j]; vi[c][j] = iv[j]; }
  }

  // ---- LN1 ----
  float s = 0.f;
#pragma unroll
  for (int c = 0; c < 4; ++c)
#pragma unroll
    for (int j = 0; j < 4; ++j) s += vi[c][j];
  s = red4(s);
  float mu = s * (1.f / D);
  float v2 = 0.f;
#pragma unroll
  for (int c = 0; c < 4; ++c)
#pragma unroll
    for (int j = 0; j < 4; ++j) {
      float d = vi[c][j] - mu;
      v2 += d * d;
    }
  v2 = red4(v2);
  float rs = rsqrtf(v2 * (1.f / D) + EPS);

  float x[4][4];
  float bd1 = 0.f, bd2 = 0.f;      // bias-dot partials
#pragma unroll
  for (int c = 0; c < 4; ++c) {
    int k0 = c * 16 + grp * 4;
    f32x4 gv  = *(const f32x4*)(g1 + k0);
    f32x4 bv  = *(const f32x4*)(b1 + k0);
    f32x4 b1v = *(const f32x4*)(W1b + k0);
    f32x4 b2v = *(const f32x4*)(W2b + k0);
#pragma unroll
    for (int j = 0; j < 4; ++j) {
      x[c][j] = (vi[c][j] - mu) * rs * gv[j] + bv[j];
      bd1 += b1v[j] * vq[c][j];
      bd2 += b2v[j] * x[c][j];
    }
  }

  // ---- f16 fragments ----
  f16x4 xh[4], qh[4];
#pragma unroll
  for (int c = 0; c < 4; ++c)
#pragma unroll
    for (int j = 0; j < 4; ++j) {
      xh[c][j] = (f16)x[c][j];
      qh[c][j] = (f16)vq[c][j];
    }

  // ---- dense = X @ Ww + Wb ----
#pragma unroll
  for (int t = 0; t < 4; ++t) {
    f32x4 acc = {0.f, 0.f, 0.f, 0.f};
#pragma unroll
    for (int c = 0; c < 4; ++c) {
      f16x4 w = *(const f16x4*)(wt + (t * 16 + mloc) * 64 + c * 16 + grp * 4);
      acc = __builtin_amdgcn_mfma_f32_16x16x16f16(xh[c], w, acc, 0, 0, 0);
    }
    float wb = Wb[t * 16 + mloc];
#pragma unroll
    for (int r = 0; r < 4; ++r) {
      int row = nb + grp * 4 + r;
      if (row < N) dense[(size_t)row * D + t * 16 + mloc] = acc[r] + wb;
    }
  }

  // ---- scores: Y1 = W1^T Q^T, Y2 = W2^T X^T, then lane-local dots ----
  float dot1 = bd1, dot2 = bd2;
#pragma unroll
  for (int t = 0; t < 4; ++t) {
    f32x4 a1 = {0.f, 0.f, 0.f, 0.f}, a2 = {0.f, 0.f, 0.f, 0.f};
#pragma unroll
    for (int c = 0; c < 4; ++c) {
      int off = (t * 16 + mloc) * 64 + c * 16 + grp * 4;
      f16x4 w1 = *(const f16x4*)(wt + 4096 + off);
      f16x4 w2 = *(const f16x4*)(wt + 8192 + off);
      a1 = __builtin_amdgcn_mfma_f32_16x16x16f16(w1, qh[c], a1, 0, 0, 0);
      a2 = __builtin_amdgcn_mfma_f32_16x16x16f16(w2, xh[c], a2, 0, 0, 0);
    }
    // lane holds Y[d, nb+mloc] for d = t*16 + grp*4 + r; q[m,d] == vq[t][r]
#pragma unroll
    for (int r = 0; r < 4; ++r) {
      dot1 += a1[r] * vq[t][r];
      dot2 += a2[r] * x[t][r];
    }
  }
  dot1 = red4(dot1);
  dot2 = red4(dot2);
  if (grp == 0 && mv) {
    s1[m] = tanhf(dot1);
    s2[m] = tanhf(dot2);
  }
}

// ---------------------------------------------------------------------------
// CSR row pointers from the sorted edge_row array.
// ---------------------------------------------------------------------------
__global__ void rowptr_kernel(const int* __restrict__ erow,
                              int* __restrict__ row_ptr, int E, int N)
{
  int e = blockIdx.x * blockDim.x + threadIdx.x;
  if (e >= E) return;
  int r = erow[e];
  if (e == 0) {
    for (int rr = 0; rr <= r; ++rr) row_ptr[rr] = 0;
  } else {
    int rp = erow[e - 1];
    for (int rr = rp + 1; rr <= r; ++rr) row_ptr[rr] = e;
  }
  if (e == E - 1) {
    for (int rr = r + 1; rr <= N; ++rr) row_ptr[rr] = E;
  }
}

// ---------------------------------------------------------------------------
// Edge kernel: per-row softmax + SpMM + LN2, wave-per-row, lane = feature.
// ---------------------------------------------------------------------------
__global__ __launch_bounds__(256) void edge_kernel(
    const int* __restrict__ row_ptr, const int* __restrict__ ecol,
    const float* __restrict__ s1, const float* __restrict__ s2,
    const float* __restrict__ dense,
    const float* __restrict__ g2, const float* __restrict__ b2,
    float* __restrict__ out, int N)
{
  const int lane = threadIdx.x & 63;
  const int row  = blockIdx.x * (blockDim.x >> 6) + (threadIdx.x >> 6);
  if (row >= N) return;

  const int start = row_ptr[row];
  const int end   = row_ptr[row + 1];
  const int deg   = end - start;
  const float s1i = s1[row];

  float acc = 0.f, denom = 0.f;

  if (deg <= 64) {
    int   c = 0;
    float l = -INFINITY;
    if (lane < deg) {
      c = ecol[start + lane];
      l = leaky(s1i + s2[c]);
    }
    float m = wave_max(l);
    float w = (lane < deg) ? __expf(l - m) : 0.f;
    denom = wave_sum(w);
#pragma unroll 4
    for (int e = 0; e < deg; ++e) {
      int   ce = bcast_i(c, e);
      float we = bcast(w, e);
      acc = fmaf(we, dense[(size_t)ce * D + lane], acc);
    }
  } else {
    float m = -INFINITY;
    for (int e = start + lane; e < end; e += 64)
      m = fmaxf(m, leaky(s1i + s2[ecol[e]]));
    m = wave_max(m);

    float wsum = 0.f;
    for (int b = start; b < end; b += 64) {
      int nb = min(64, end - b);
      int   c = 0;
      float w = 0.f;
      if (lane < nb) {
        c = ecol[b + lane];
        w = __expf(leaky(s1i + s2[c]) - m);
      }
      wsum += w;
#pragma unroll 4
      for (int e = 0; e < nb; ++e) {
        int   ce = bcast_i(c, e);
        float we = bcast(w, e);
        acc = fmaf(we, dense[(size_t)ce * D + lane], acc);
      }
    }
    denom = wave_sum(wsum);
  }

  float o = (deg > 0) ? (acc / denom) : 0.f;

  float mu  = wave_sum(o) * (1.f / D);
  float dv  = o - mu;
  float var = wave_sum(dv * dv) * (1.f / D);
  out[(size_t)row * D + lane] = dv * rsqrtf(var + EPS) * g2[lane] + b2[lane];
}

// ---------------------------------------------------------------------------
extern "C" void kernel_launch(void* const* d_in, const int* in_sizes, int n_in,
                              void* d_out, int out_size, void* d_ws, size_t ws_size,
                              hipStream_t stream)
{
  const float* query  = (const float*)d_in[0];
  const float* input_ = (const float*)d_in[1];
  const int*   erow   = (const int*)d_in[2];
  const int*   ecol   = (const int*)d_in[3];
  const float* Ww     = (const float*)d_in[4];
  const float* Wb     = (const float*)d_in[5];
  const float* W1w    = (const float*)d_in[6];
  const float* W1b    = (const float*)d_in[7];
  const float* W2w    = (const float*)d_in[8];
  const float* W2b    = (const float*)d_in[9];
  const float* g1     = (const float*)d_in[10];
  const float* b1     = (const float*)d_in[11];
  const float* g2     = (const float*)d_in[12];
  const float* b2     = (const float*)d_in[13];

  const int N = in_sizes[0] / D;
  const int E = in_sizes[2];
  float* out = (float*)d_out;

  // ws layout: dense [N*D] f32 | s1 [N] | s2 [N] | row_ptr [N+1] | wt (f16, 16B-aligned)
  char* ws = (char*)d_ws;
  float* dense   = (float*)ws;
  float* s1      = dense + (size_t)N * D;
  float* s2      = s1 + N;
  int*   row_ptr = (int*)(s2 + N);
  uintptr_t wtp  = (uintptr_t)(row_ptr + N + 1);
  wtp = (wtp + 15) & ~(uintptr_t)15;
  f16* wt = (f16*)wtp;

  wprep_kernel<<<(3 * 4096 + 255) / 256, 256, 0, stream>>>(Ww, W1w, W2w, wt);
  node_kernel<<<(N + 63) / 64, 256, 0, stream>>>(query, input_, wt, Wb, W1b,
                                                 W2b, g1, b1, dense, s1, s2, N);
  rowptr_kernel<<<(E + 255) / 256, 256, 0, stream>>>(erow, row_ptr, E, N);
  edge_kernel<<<(N + 3) / 4, 256, 0, stream>>>(row_ptr, ecol, s1, s2, dense,
                                               g2, b2, out, N);
}

// Round 4
// 131.415 us; speedup vs baseline: 2.2249x; 1.3246x over previous
//
#include <hip/hip_runtime.h>
#include <math.h>

#define D 64
#define EPS 1e-6f
#define SLOPE 0.2f

typedef _Float16 f16;
typedef _Float16 f16x4 __attribute__((ext_vector_type(4)));
typedef float f32x4 __attribute__((ext_vector_type(4)));

__device__ __forceinline__ float wave_sum(float v) {
#pragma unroll
  for (int m = 32; m > 0; m >>= 1) v += __shfl_xor(v, m, 64);
  return v;
}
// reduce across the 4 lane-groups (lanes differing in bits 4,5) -> all lanes
__device__ __forceinline__ float red4(float v) {
  v += __shfl_xor(v, 16, 64);
  v += __shfl_xor(v, 32, 64);
  return v;
}
__device__ __forceinline__ float bcast(float v, int k) {
  return __int_as_float(__builtin_amdgcn_readlane(__float_as_int(v), k));
}
__device__ __forceinline__ int bcast_i(int v, int k) {
  return __builtin_amdgcn_readlane(v, k);
}
__device__ __forceinline__ float leaky(float l) {
  return (l > 0.f) ? l : SLOPE * l;
}

// ---------------------------------------------------------------------------
// W prep: transpose the three [k][n] f32 weight matrices to n-major f16
// wt[mat*4096 + n*64 + k] so MFMA fragments are contiguous 8B loads.
// ---------------------------------------------------------------------------
__global__ void wprep_kernel(const float* __restrict__ Ww,
                             const float* __restrict__ W1w,
                             const float* __restrict__ W2w,
                             f16* __restrict__ wt)
{
  int i = blockIdx.x * blockDim.x + threadIdx.x;   // 0 .. 3*4096-1
  if (i >= 3 * 4096) return;
  int mat = i >> 12, idx = i & 4095;
  int n = idx >> 6, k = idx & 63;
  const float* src = (mat == 0) ? Ww : (mat == 1) ? W1w : W2w;
  wt[i] = (f16)src[k * 64 + n];
}

// ---------------------------------------------------------------------------
// Node kernel (MFMA): per wave, 16 nodes.  See R2 notes: C-row index == A-k
// index for 16x16x16, so score dots are lane-local after Y = W^T Q^T.
// ---------------------------------------------------------------------------
__global__ __launch_bounds__(256) void node_kernel(
    const float* __restrict__ query, const float* __restrict__ input_,
    const f16* __restrict__ wt,
    const float* __restrict__ Wb,  const float* __restrict__ W1b,
    const float* __restrict__ W2b,
    const float* __restrict__ g1,  const float* __restrict__ b1,
    float* __restrict__ dense, float* __restrict__ s1, float* __restrict__ s2,
    int N)
{
  const int lane = threadIdx.x & 63;
  const int grp  = lane >> 4;        // 0..3
  const int mloc = lane & 15;        // node within tile (A/B role)
  const int wv   = threadIdx.x >> 6;
  const int nb   = blockIdx.x * 64 + wv * 16;
  const int m    = nb + mloc;
  const bool mv  = (m < N);

  float vq[4][4], vi[4][4];
#pragma unroll
  for (int c = 0; c < 4; ++c) {
    int k0 = c * 16 + grp * 4;
    f32x4 qv = {0.f, 0.f, 0.f, 0.f}, iv = {0.f, 0.f, 0.f, 0.f};
    if (mv) {
      qv = *(const f32x4*)(query  + (size_t)m * D + k0);
      iv = *(const f32x4*)(input_ + (size_t)m * D + k0);
    }
#pragma unroll
    for (int j = 0; j < 4; ++j) { vq[c][j] = qv[j]; vi[c][j] = iv[j]; }
  }

  // ---- LN1 ----
  float s = 0.f;
#pragma unroll
  for (int c = 0; c < 4; ++c)
#pragma unroll
    for (int j = 0; j < 4; ++j) s += vi[c][j];
  s = red4(s);
  float mu = s * (1.f / D);
  float v2 = 0.f;
#pragma unroll
  for (int c = 0; c < 4; ++c)
#pragma unroll
    for (int j = 0; j < 4; ++j) {
      float d = vi[c][j] - mu;
      v2 += d * d;
    }
  v2 = red4(v2);
  float rs = rsqrtf(v2 * (1.f / D) + EPS);

  float x[4][4];
  float bd1 = 0.f, bd2 = 0.f;      // bias-dot partials
#pragma unroll
  for (int c = 0; c < 4; ++c) {
    int k0 = c * 16 + grp * 4;
    f32x4 gv  = *(const f32x4*)(g1 + k0);
    f32x4 bv  = *(const f32x4*)(b1 + k0);
    f32x4 b1v = *(const f32x4*)(W1b + k0);
    f32x4 b2v = *(const f32x4*)(W2b + k0);
#pragma unroll
    for (int j = 0; j < 4; ++j) {
      x[c][j] = (vi[c][j] - mu) * rs * gv[j] + bv[j];
      bd1 += b1v[j] * vq[c][j];
      bd2 += b2v[j] * x[c][j];
    }
  }

  f16x4 xh[4], qh[4];
#pragma unroll
  for (int c = 0; c < 4; ++c)
#pragma unroll
    for (int j = 0; j < 4; ++j) {
      xh[c][j] = (f16)x[c][j];
      qh[c][j] = (f16)vq[c][j];
    }

  // ---- dense = X @ Ww + Wb ----
#pragma unroll
  for (int t = 0; t < 4; ++t) {
    f32x4 acc = {0.f, 0.f, 0.f, 0.f};
#pragma unroll
    for (int c = 0; c < 4; ++c) {
      f16x4 w = *(const f16x4*)(wt + (t * 16 + mloc) * 64 + c * 16 + grp * 4);
      acc = __builtin_amdgcn_mfma_f32_16x16x16f16(xh[c], w, acc, 0, 0, 0);
    }
    float wb = Wb[t * 16 + mloc];
#pragma unroll
    for (int r = 0; r < 4; ++r) {
      int row = nb + grp * 4 + r;
      if (row < N) dense[(size_t)row * D + t * 16 + mloc] = acc[r] + wb;
    }
  }

  // ---- scores ----
  float dot1 = bd1, dot2 = bd2;
#pragma unroll
  for (int t = 0; t < 4; ++t) {
    f32x4 a1 = {0.f, 0.f, 0.f, 0.f}, a2 = {0.f, 0.f, 0.f, 0.f};
#pragma unroll
    for (int c = 0; c < 4; ++c) {
      int off = (t * 16 + mloc) * 64 + c * 16 + grp * 4;
      f16x4 w1 = *(const f16x4*)(wt + 4096 + off);
      f16x4 w2 = *(const f16x4*)(wt + 8192 + off);
      a1 = __builtin_amdgcn_mfma_f32_16x16x16f16(w1, qh[c], a1, 0, 0, 0);
      a2 = __builtin_amdgcn_mfma_f32_16x16x16f16(w2, xh[c], a2, 0, 0, 0);
    }
#pragma unroll
    for (int r = 0; r < 4; ++r) {
      dot1 += a1[r] * vq[t][r];
      dot2 += a2[r] * x[t][r];
    }
  }
  dot1 = red4(dot1);
  dot2 = red4(dot2);
  if (grp == 0 && mv) {
    s1[m] = tanhf(dot1);
    s2[m] = tanhf(dot2);
  }
}

// ---------------------------------------------------------------------------
// CSR row pointers from the sorted edge_row array.
// ---------------------------------------------------------------------------
__global__ void rowptr_kernel(const int* __restrict__ erow,
                              int* __restrict__ row_ptr, int E, int N)
{
  int e = blockIdx.x * blockDim.x + threadIdx.x;
  if (e >= E) return;
  int r = erow[e];
  if (e == 0) {
    for (int rr = 0; rr <= r; ++rr) row_ptr[rr] = 0;
  } else {
    int rp = erow[e - 1];
    for (int rr = rp + 1; rr <= r; ++rr) row_ptr[rr] = e;
  }
  if (e == E - 1) {
    for (int rr = r + 1; rr <= N; ++rr) row_ptr[rr] = E;
  }
}

// ---------------------------------------------------------------------------
// Edge kernel: single-pass softmax (tanh-bounded logits -> exp without max
// subtraction is numerically safe: l in (-0.4, 2], exp(l) in [0.67, 7.39];
// exp(l)/sum == exp(l-m)/sum(exp(l-m)) exactly in math, within f32 rounding
// here).  Per row: lane-per-edge weight compute, then readlane-broadcast
// accumulate with two independent fma chains, 4 loads in flight.
// ---------------------------------------------------------------------------
__global__ __launch_bounds__(256) void edge_kernel(
    const int* __restrict__ row_ptr, const int* __restrict__ ecol,
    const float* __restrict__ s1, const float* __restrict__ s2,
    const float* __restrict__ dense,
    const float* __restrict__ g2, const float* __restrict__ b2,
    float* __restrict__ out, int N)
{
  const int lane = threadIdx.x & 63;
  const int row  = blockIdx.x * (blockDim.x >> 6) + (threadIdx.x >> 6);
  if (row >= N) return;

  const int start = row_ptr[row];
  const int end   = row_ptr[row + 1];
  const int deg   = end - start;
  const float s1i = s1[row];

  float acc0 = 0.f, acc1 = 0.f, denom = 0.f;

  if (deg <= 64) {
    int   c = 0;
    float w = 0.f;
    if (lane < deg) {
      c = ecol[start + lane];
      w = __expf(leaky(s1i + s2[c]));
    }
    denom = wave_sum(w);
    int e = 0;
    for (; e + 4 <= deg; e += 4) {
      int c0 = bcast_i(c, e + 0), c1 = bcast_i(c, e + 1);
      int c2 = bcast_i(c, e + 2), c3 = bcast_i(c, e + 3);
      float d0 = dense[(size_t)c0 * D + lane];
      float d1 = dense[(size_t)c1 * D + lane];
      float d2 = dense[(size_t)c2 * D + lane];
      float d3 = dense[(size_t)c3 * D + lane];
      acc0 = fmaf(bcast(w, e + 0), d0, acc0);
      acc1 = fmaf(bcast(w, e + 1), d1, acc1);
      acc0 = fmaf(bcast(w, e + 2), d2, acc0);
      acc1 = fmaf(bcast(w, e + 3), d3, acc1);
    }
    for (; e < deg; ++e)
      acc0 = fmaf(bcast(w, e), dense[(size_t)bcast_i(c, e) * D + lane], acc0);
  } else {
    float wsum = 0.f;
    for (int b = start; b < end; b += 64) {
      int nb = min(64, end - b);
      int   c = 0;
      float w = 0.f;
      if (lane < nb) {
        c = ecol[b + lane];
        w = __expf(leaky(s1i + s2[c]));
      }
      wsum += w;
      int e = 0;
      for (; e + 4 <= nb; e += 4) {
        int c0 = bcast_i(c, e + 0), c1 = bcast_i(c, e + 1);
        int c2 = bcast_i(c, e + 2), c3 = bcast_i(c, e + 3);
        float d0 = dense[(size_t)c0 * D + lane];
        float d1 = dense[(size_t)c1 * D + lane];
        float d2 = dense[(size_t)c2 * D + lane];
        float d3 = dense[(size_t)c3 * D + lane];
        acc0 = fmaf(bcast(w, e + 0), d0, acc0);
        acc1 = fmaf(bcast(w, e + 1), d1, acc1);
        acc0 = fmaf(bcast(w, e + 2), d2, acc0);
        acc1 = fmaf(bcast(w, e + 3), d3, acc1);
      }
      for (; e < nb; ++e)
        acc0 = fmaf(bcast(w, e), dense[(size_t)bcast_i(c, e) * D + lane], acc0);
    }
    denom = wave_sum(wsum);
  }

  float o = (deg > 0) ? ((acc0 + acc1) / denom) : 0.f;

  // LN2: fused mean+meansq butterfly (two interleaved chains)
  float a = o, b = o * o;
#pragma unroll
  for (int m = 32; m > 0; m >>= 1) {
    a += __shfl_xor(a, m, 64);
    b += __shfl_xor(b, m, 64);
  }
  float mu  = a * (1.f / D);
  float var = b * (1.f / D) - mu * mu;
  var = fmaxf(var, 0.f);
  out[(size_t)row * D + lane] =
      (o - mu) * rsqrtf(var + EPS) * g2[lane] + b2[lane];
}

// ---------------------------------------------------------------------------
extern "C" void kernel_launch(void* const* d_in, const int* in_sizes, int n_in,
                              void* d_out, int out_size, void* d_ws, size_t ws_size,
                              hipStream_t stream)
{
  const float* query  = (const float*)d_in[0];
  const float* input_ = (const float*)d_in[1];
  const int*   erow   = (const int*)d_in[2];
  const int*   ecol   = (const int*)d_in[3];
  const float* Ww     = (const float*)d_in[4];
  const float* Wb     = (const float*)d_in[5];
  const float* W1w    = (const float*)d_in[6];
  const float* W1b    = (const float*)d_in[7];
  const float* W2w    = (const float*)d_in[8];
  const float* W2b    = (const float*)d_in[9];
  const float* g1     = (const float*)d_in[10];
  const float* b1     = (const float*)d_in[11];
  const float* g2     = (const float*)d_in[12];
  const float* b2     = (const float*)d_in[13];

  const int N = in_sizes[0] / D;
  const int E = in_sizes[2];
  float* out = (float*)d_out;

  // ws layout: dense [N*D] f32 | s1 [N] | s2 [N] | row_ptr [N+1] | wt (f16)
  char* ws = (char*)d_ws;
  float* dense   = (float*)ws;
  float* s1      = dense + (size_t)N * D;
  float* s2      = s1 + N;
  int*   row_ptr = (int*)(s2 + N);
  uintptr_t wtp  = (uintptr_t)(row_ptr + N + 1);
  wtp = (wtp + 15) & ~(uintptr_t)15;
  f16* wt = (f16*)wtp;

  wprep_kernel<<<(3 * 4096 + 255) / 256, 256, 0, stream>>>(Ww, W1w, W2w, wt);
  node_kernel<<<(N + 63) / 64, 256, 0, stream>>>(query, input_, wt, Wb, W1b,
                                                 W2b, g1, b1, dense, s1, s2, N);
  rowptr_kernel<<<(E + 255) / 256, 256, 0, stream>>>(erow, row_ptr, E, N);
  edge_kernel<<<(N + 3) / 4, 256, 0, stream>>>(row_ptr, ecol, s1, s2, dense,
                                               g2, b2, out, N);
}

// Round 5
// 126.299 us; speedup vs baseline: 2.3150x; 1.0405x over previous
//
#include <hip/hip_runtime.h>
#include <math.h>

#define D 64
#define EPS 1e-6f
#define SLOPE 0.2f

typedef _Float16 f16;
typedef _Float16 f16x4 __attribute__((ext_vector_type(4)));
typedef float f32x4 __attribute__((ext_vector_type(4)));

__device__ __forceinline__ float wave_sum(float v) {
#pragma unroll
  for (int m = 32; m > 0; m >>= 1) v += __shfl_xor(v, m, 64);
  return v;
}
__device__ __forceinline__ float red4(float v) {
  v += __shfl_xor(v, 16, 64);
  v += __shfl_xor(v, 32, 64);
  return v;
}
__device__ __forceinline__ float leaky(float l) {
  return (l > 0.f) ? l : SLOPE * l;
}
__device__ __forceinline__ float bperm_f(int byte_addr, float v) {
  return __int_as_float(
      __builtin_amdgcn_ds_bpermute(byte_addr, __float_as_int(v)));
}
__device__ __forceinline__ int bperm_i(int byte_addr, int v) {
  return __builtin_amdgcn_ds_bpermute(byte_addr, v);
}

// ---------------------------------------------------------------------------
// W prep: transpose the three [k][n] f32 weight matrices to n-major f16.
// ---------------------------------------------------------------------------
__global__ void wprep_kernel(const float* __restrict__ Ww,
                             const float* __restrict__ W1w,
                             const float* __restrict__ W2w,
                             f16* __restrict__ wt)
{
  int i = blockIdx.x * blockDim.x + threadIdx.x;
  if (i >= 3 * 4096) return;
  int mat = i >> 12, idx = i & 4095;
  int n = idx >> 6, k = idx & 63;
  const float* src = (mat == 0) ? Ww : (mat == 1) ? W1w : W2w;
  wt[i] = (f16)src[k * 64 + n];
}

// ---------------------------------------------------------------------------
// Node kernel (MFMA, 16 nodes/wave): LN1, dense (f16 out), scores s1/s2.
// ---------------------------------------------------------------------------
__global__ __launch_bounds__(256) void node_kernel(
    const float* __restrict__ query, const float* __restrict__ input_,
    const f16* __restrict__ wt,
    const float* __restrict__ Wb,  const float* __restrict__ W1b,
    const float* __restrict__ W2b,
    const float* __restrict__ g1,  const float* __restrict__ b1,
    f16* __restrict__ dense_h, float* __restrict__ s1, float* __restrict__ s2,
    int N)
{
  const int lane = threadIdx.x & 63;
  const int grp  = lane >> 4;
  const int mloc = lane & 15;
  const int wv   = threadIdx.x >> 6;
  const int nb   = blockIdx.x * 64 + wv * 16;
  const int m    = nb + mloc;
  const bool mv  = (m < N);

  float vq[4][4], vi[4][4];
#pragma unroll
  for (int c = 0; c < 4; ++c) {
    int k0 = c * 16 + grp * 4;
    f32x4 qv = {0.f, 0.f, 0.f, 0.f}, iv = {0.f, 0.f, 0.f, 0.f};
    if (mv) {
      qv = *(const f32x4*)(query  + (size_t)m * D + k0);
      iv = *(const f32x4*)(input_ + (size_t)m * D + k0);
    }
#pragma unroll
    for (int j = 0; j < 4; ++j) { vq[c][j] = qv[j]; vi[c][j] = iv[j]; }
  }

  // LN1
  float s = 0.f;
#pragma unroll
  for (int c = 0; c < 4; ++c)
#pragma unroll
    for (int j = 0; j < 4; ++j) s += vi[c][j];
  s = red4(s);
  float mu = s * (1.f / D);
  float v2 = 0.f;
#pragma unroll
  for (int c = 0; c < 4; ++c)
#pragma unroll
    for (int j = 0; j < 4; ++j) {
      float d = vi[c][j] - mu;
      v2 += d * d;
    }
  v2 = red4(v2);
  float rs = rsqrtf(v2 * (1.f / D) + EPS);

  float x[4][4];
  float bd1 = 0.f, bd2 = 0.f;
#pragma unroll
  for (int c = 0; c < 4; ++c) {
    int k0 = c * 16 + grp * 4;
    f32x4 gv  = *(const f32x4*)(g1 + k0);
    f32x4 bv  = *(const f32x4*)(b1 + k0);
    f32x4 b1v = *(const f32x4*)(W1b + k0);
    f32x4 b2v = *(const f32x4*)(W2b + k0);
#pragma unroll
    for (int j = 0; j < 4; ++j) {
      x[c][j] = (vi[c][j] - mu) * rs * gv[j] + bv[j];
      bd1 += b1v[j] * vq[c][j];
      bd2 += b2v[j] * x[c][j];
    }
  }

  f16x4 xh[4], qh[4];
#pragma unroll
  for (int c = 0; c < 4; ++c)
#pragma unroll
    for (int j = 0; j < 4; ++j) {
      xh[c][j] = (f16)x[c][j];
      qh[c][j] = (f16)vq[c][j];
    }

  // dense = X @ Ww + Wb  -> f16
#pragma unroll
  for (int t = 0; t < 4; ++t) {
    f32x4 acc = {0.f, 0.f, 0.f, 0.f};
#pragma unroll
    for (int c = 0; c < 4; ++c) {
      f16x4 w = *(const f16x4*)(wt + (t * 16 + mloc) * 64 + c * 16 + grp * 4);
      acc = __builtin_amdgcn_mfma_f32_16x16x16f16(xh[c], w, acc, 0, 0, 0);
    }
    float wb = Wb[t * 16 + mloc];
#pragma unroll
    for (int r = 0; r < 4; ++r) {
      int row = nb + grp * 4 + r;
      if (row < N) dense_h[(size_t)row * D + t * 16 + mloc] = (f16)(acc[r] + wb);
    }
  }

  // scores (C-row index == A-k index trick, see R2)
  float dot1 = bd1, dot2 = bd2;
#pragma unroll
  for (int t = 0; t < 4; ++t) {
    f32x4 a1 = {0.f, 0.f, 0.f, 0.f}, a2 = {0.f, 0.f, 0.f, 0.f};
#pragma unroll
    for (int c = 0; c < 4; ++c) {
      int off = (t * 16 + mloc) * 64 + c * 16 + grp * 4;
      f16x4 w1 = *(const f16x4*)(wt + 4096 + off);
      f16x4 w2 = *(const f16x4*)(wt + 8192 + off);
      a1 = __builtin_amdgcn_mfma_f32_16x16x16f16(w1, qh[c], a1, 0, 0, 0);
      a2 = __builtin_amdgcn_mfma_f32_16x16x16f16(w2, xh[c], a2, 0, 0, 0);
    }
#pragma unroll
    for (int r = 0; r < 4; ++r) {
      dot1 += a1[r] * vq[t][r];
      dot2 += a2[r] * x[t][r];
    }
  }
  dot1 = red4(dot1);
  dot2 = red4(dot2);
  if (grp == 0 && mv) {
    s1[m] = tanhf(dot1);
    s2[m] = tanhf(dot2);
  }
}

// ---------------------------------------------------------------------------
// CSR row pointers from the sorted edge_row array.
// ---------------------------------------------------------------------------
__global__ void rowptr_kernel(const int* __restrict__ erow,
                              int* __restrict__ row_ptr, int E, int N)
{
  int e = blockIdx.x * blockDim.x + threadIdx.x;
  if (e >= E) return;
  int r = erow[e];
  if (e == 0) {
    for (int rr = 0; rr <= r; ++rr) row_ptr[rr] = 0;
  } else {
    int rp = erow[e - 1];
    for (int rr = rp + 1; rr <= r; ++rr) row_ptr[rr] = e;
  }
  if (e == E - 1) {
    for (int rr = r + 1; rr <= N; ++rr) row_ptr[rr] = E;
  }
}

// ---------------------------------------------------------------------------
// Edge-parallel weight kernel: ew[e] = exp(leaky(s1[erow]+s2[ecol])).
// Random s2 gather is latency-hidden by massive TLP here.
// (tanh-bounded logits -> exp without max subtraction is safe; see R3.)
// ---------------------------------------------------------------------------
__global__ void weight_kernel(const int* __restrict__ erow,
                              const int* __restrict__ ecol,
                              const float* __restrict__ s1,
                              const float* __restrict__ s2,
                              float* __restrict__ ew, int E)
{
  int e = blockIdx.x * blockDim.x + threadIdx.x;
  if (e >= E) return;
  float l = s1[erow[e]] + s2[ecol[e]];
  ew[e] = __expf(leaky(l));
}

// ---------------------------------------------------------------------------
// Edge kernel: wave-per-row.  lane = 16*eg + fl.  Each iteration the 4
// sub-groups (eg) load 4 different edges' dense rows as f16x4 (8B/lane,
// 1KB/wave VMEM) and fma into per-lane f32x4 partials; (wn, col) are
// redistributed per-iteration with one ds_bpermute pair.  Weights are
// pre-normalized (wn = w/denom) so there is no epilogue divide.  Cross-group
// xor-reduce + 16-lane LN2 + dwordx4 store.
// ---------------------------------------------------------------------------
__global__ __launch_bounds__(256) void edge_kernel(
    const int* __restrict__ row_ptr, const int* __restrict__ ecol,
    const float* __restrict__ ew, const f16* __restrict__ dense_h,
    const float* __restrict__ g2, const float* __restrict__ b2,
    float* __restrict__ out, int N)
{
  const int lane = threadIdx.x & 63;
  const int eg   = lane >> 4;          // edge sub-group 0..3
  const int fl   = lane & 15;          // feature quad 0..15
  const int eg4  = eg << 2;            // bpermute byte offset component
  const int row  = blockIdx.x * (blockDim.x >> 6) + (threadIdx.x >> 6);
  if (row >= N) return;

  const int start = row_ptr[row];
  const int end   = row_ptr[row + 1];
  const int deg   = end - start;

  f32x4 acc = {0.f, 0.f, 0.f, 0.f};

  if (deg > 0 && deg <= 64) {
    int   c = 0;
    float w = 0.f;
    if (lane < deg) {
      c = ecol[start + lane];
      w = ew[start + lane];
    }
    float denom = wave_sum(w);
    float wn = w * __frcp_rn(denom);
    const int nit = (deg + 3) >> 2;
    for (int it = 0; it < nit; ++it) {
      int a = (it << 4) + eg4;                  // byte addr = 4*(it*4+eg)
      float wb = bperm_f(a, wn);
      int   cb = bperm_i(a, c);
      f16x4 d = *(const f16x4*)(dense_h + (size_t)cb * D + (fl << 2));
#pragma unroll
      for (int j = 0; j < 4; ++j)
        acc[j] = fmaf((float)d[j], wb, acc[j]);
    }
  } else if (deg > 64) {
    float wl = 0.f;
    for (int b = start + lane; b < end; b += 64) wl += ew[b];
    float inv = __frcp_rn(wave_sum(wl));
    for (int b = start; b < end; b += 64) {
      int nb = min(64, end - b);
      int   c = 0;
      float wn = 0.f;
      if (lane < nb) {
        c = ecol[b + lane];
        wn = ew[b + lane] * inv;
      }
      const int nit = (nb + 3) >> 2;
      for (int it = 0; it < nit; ++it) {
        int a = (it << 4) + eg4;
        float wb = bperm_f(a, wn);
        int   cb = bperm_i(a, c);
        f16x4 d = *(const f16x4*)(dense_h + (size_t)cb * D + (fl << 2));
#pragma unroll
        for (int j = 0; j < 4; ++j)
          acc[j] = fmaf((float)d[j], wb, acc[j]);
      }
    }
  }

  // cross-group reduce: every lane ends with sums for features 4*fl..4*fl+3
#pragma unroll
  for (int j = 0; j < 4; ++j) {
    acc[j] += __shfl_xor(acc[j], 16, 64);
    acc[j] += __shfl_xor(acc[j], 32, 64);
  }

  // LN2 over the 16-lane feature groups (fused mean / mean-square)
  float s = 0.f, t = 0.f;
#pragma unroll
  for (int j = 0; j < 4; ++j) {
    s += acc[j];
    t += acc[j] * acc[j];
  }
#pragma unroll
  for (int m = 8; m > 0; m >>= 1) {
    s += __shfl_xor(s, m, 64);
    t += __shfl_xor(t, m, 64);
  }
  float mu  = s * (1.f / D);
  float var = fmaxf(t * (1.f / D) - mu * mu, 0.f);
  float rs  = rsqrtf(var + EPS);

  if (eg == 0) {
    f32x4 gv = *(const f32x4*)(g2 + (fl << 2));
    f32x4 bv = *(const f32x4*)(b2 + (fl << 2));
    f32x4 o;
#pragma unroll
    for (int j = 0; j < 4; ++j)
      o[j] = (acc[j] - mu) * rs * gv[j] + bv[j];
    *(f32x4*)(out + (size_t)row * D + (fl << 2)) = o;
  }
}

// ---------------------------------------------------------------------------
extern "C" void kernel_launch(void* const* d_in, const int* in_sizes, int n_in,
                              void* d_out, int out_size, void* d_ws, size_t ws_size,
                              hipStream_t stream)
{
  const float* query  = (const float*)d_in[0];
  const float* input_ = (const float*)d_in[1];
  const int*   erow   = (const int*)d_in[2];
  const int*   ecol   = (const int*)d_in[3];
  const float* Ww     = (const float*)d_in[4];
  const float* Wb     = (const float*)d_in[5];
  const float* W1w    = (const float*)d_in[6];
  const float* W1b    = (const float*)d_in[7];
  const float* W2w    = (const float*)d_in[8];
  const float* W2b    = (const float*)d_in[9];
  const float* g1     = (const float*)d_in[10];
  const float* b1     = (const float*)d_in[11];
  const float* g2     = (const float*)d_in[12];
  const float* b2     = (const float*)d_in[13];

  const int N = in_sizes[0] / D;
  const int E = in_sizes[2];
  float* out = (float*)d_out;

  // ws layout: dense_h f16[N*D] | s1[N] | s2[N] | row_ptr[N+1] | ew[E] | wt
  char* ws = (char*)d_ws;
  f16*   dense_h = (f16*)ws;
  float* s1      = (float*)(ws + (size_t)N * D * sizeof(f16));
  float* s2      = s1 + N;
  int*   row_ptr = (int*)(s2 + N);
  float* ew      = (float*)(row_ptr + N + 1);
  uintptr_t wtp  = (uintptr_t)(ew + E);
  wtp = (wtp + 15) & ~(uintptr_t)15;
  f16* wt = (f16*)wtp;

  wprep_kernel<<<(3 * 4096 + 255) / 256, 256, 0, stream>>>(Ww, W1w, W2w, wt);
  node_kernel<<<(N + 63) / 64, 256, 0, stream>>>(query, input_, wt, Wb, W1b,
                                                 W2b, g1, b1, dense_h, s1, s2, N);
  rowptr_kernel<<<(E + 255) / 256, 256, 0, stream>>>(erow, row_ptr, E, N);
  weight_kernel<<<(E + 255) / 256, 256, 0, stream>>>(erow, ecol, s1, s2, ew, E);
  edge_kernel<<<(N + 3) / 4, 256, 0, stream>>>(row_ptr, ecol, ew, dense_h,
                                               g2, b2, out, N);
}

// Round 6
// 99.124 us; speedup vs baseline: 2.9497x; 1.2742x over previous
//
#include <hip/hip_runtime.h>
#include <math.h>

#define D 64
#define EPS 1e-6f
#define SLOPE 0.2f

typedef _Float16 f16;
typedef _Float16 f16x4 __attribute__((ext_vector_type(4)));
typedef float f32x4 __attribute__((ext_vector_type(4)));

__device__ __forceinline__ float wave_sum(float v) {
#pragma unroll
  for (int m = 32; m > 0; m >>= 1) v += __shfl_xor(v, m, 64);
  return v;
}
__device__ __forceinline__ float red4(float v) {
  v += __shfl_xor(v, 16, 64);
  v += __shfl_xor(v, 32, 64);
  return v;
}
__device__ __forceinline__ float leaky(float l) {
  return (l > 0.f) ? l : SLOPE * l;
}
__device__ __forceinline__ float bperm_f(int byte_addr, float v) {
  return __int_as_float(
      __builtin_amdgcn_ds_bpermute(byte_addr, __float_as_int(v)));
}
__device__ __forceinline__ int bperm_i(int byte_addr, int v) {
  return __builtin_amdgcn_ds_bpermute(byte_addr, v);
}

// ---------------------------------------------------------------------------
// W prep -> FRAGMENT-MAJOR f16 layout.
// frag_id = mat*16 + t*4 + c  (t = out-col tile, c = k tile)
// element  wt[frag_id*256 + lane*4 + j], lane = grp*16 + mloc:
//   value = W[mat][ c*16 + grp*4 + j ][ t*16 + mloc ]
// so each fragment load in node_kernel is one contiguous 512B wave read.
// ---------------------------------------------------------------------------
__global__ void wprep_kernel(const float* __restrict__ Ww,
                             const float* __restrict__ W1w,
                             const float* __restrict__ W2w,
                             f16* __restrict__ wt)
{
  int i = blockIdx.x * blockDim.x + threadIdx.x;
  if (i >= 3 * 4096) return;
  int mat = i >> 12, idx = i & 4095;
  int n = idx >> 6, k = idx & 63;
  const float* src = (mat == 0) ? Ww : (mat == 1) ? W1w : W2w;
  int t = n >> 4, mloc = n & 15;
  int c = k >> 4, grp = (k >> 2) & 3, j = k & 3;
  int frag = mat * 16 + t * 4 + c;
  int lane = grp * 16 + mloc;
  wt[(frag << 8) + (lane << 2) + j] = (f16)src[k * 64 + n];
}

// ---------------------------------------------------------------------------
// Node kernel v2: weights live in VGPRs (48 f16x4 fragments loaded once per
// wave), grid-stride over 16-node tiles with a 2-deep q/input prefetch
// pipeline.  2 waves/SIMD co-resident by design (512 blocks).
// ---------------------------------------------------------------------------
__global__ __launch_bounds__(256, 2) void node_kernel(
    const float* __restrict__ query, const float* __restrict__ input_,
    const f16* __restrict__ wt,
    const float* __restrict__ Wb,  const float* __restrict__ W1b,
    const float* __restrict__ W2b,
    const float* __restrict__ g1,  const float* __restrict__ b1,
    f16* __restrict__ dense_h, float* __restrict__ s1, float* __restrict__ s2,
    int N)
{
  const int lane = threadIdx.x & 63;
  const int grp  = lane >> 4;
  const int mloc = lane & 15;
  const int wave  = blockIdx.x * (blockDim.x >> 6) + (threadIdx.x >> 6);
  const int nwav  = gridDim.x * (blockDim.x >> 6);
  const int TILES = (N + 15) >> 4;

  // ---- per-wave preloads (loop-invariant) ----
  f16x4 wd[4][4], w1r[4][4], w2r[4][4];
#pragma unroll
  for (int t = 0; t < 4; ++t)
#pragma unroll
    for (int c = 0; c < 4; ++c) {
      int f = t * 4 + c;
      wd[t][c]  = *(const f16x4*)(wt + ((f)      << 8) + (lane << 2));
      w1r[t][c] = *(const f16x4*)(wt + ((16 + f) << 8) + (lane << 2));
      w2r[t][c] = *(const f16x4*)(wt + ((32 + f) << 8) + (lane << 2));
    }
  f32x4 gk[4], bk[4];
#pragma unroll
  for (int c = 0; c < 4; ++c) {
    gk[c] = *(const f32x4*)(g1 + c * 16 + grp * 4);
    bk[c] = *(const f32x4*)(b1 + c * 16 + grp * 4);
  }
  float wbr[4];
#pragma unroll
  for (int t = 0; t < 4; ++t) wbr[t] = Wb[t * 16 + mloc];

  auto prefetch = [&](f32x4* QB, f32x4* IB, int tl) {
    int m = tl * 16 + mloc;
    bool v = (tl < TILES) && (m < N);
    size_t b = (size_t)m * D;
#pragma unroll
    for (int c = 0; c < 4; ++c) {
      int k0 = c * 16 + grp * 4;
      if (v) {
        QB[c] = *(const f32x4*)(query + b + k0);
        IB[c] = *(const f32x4*)(input_ + b + k0);
      } else {
        QB[c] = (f32x4){0.f, 0.f, 0.f, 0.f};
        IB[c] = (f32x4){0.f, 0.f, 0.f, 0.f};
      }
    }
  };

  auto process = [&](f32x4* QB, f32x4* IB, int tl) {
    // LN1
    float s = 0.f;
#pragma unroll
    for (int c = 0; c < 4; ++c)
#pragma unroll
      for (int j = 0; j < 4; ++j) s += IB[c][j];
    s = red4(s);
    float mu = s * (1.f / D);
    float v2 = 0.f;
#pragma unroll
    for (int c = 0; c < 4; ++c)
#pragma unroll
      for (int j = 0; j < 4; ++j) {
        float d = IB[c][j] - mu;
        v2 += d * d;
      }
    v2 = red4(v2);
    float rs = rsqrtf(v2 * (1.f / D) + EPS);

    f16x4 xh[4], qh[4];
#pragma unroll
    for (int c = 0; c < 4; ++c)
#pragma unroll
      for (int j = 0; j < 4; ++j) {
        xh[c][j] = (f16)((IB[c][j] - mu) * rs * gk[c][j] + bk[c][j]);
        qh[c][j] = (f16)QB[c][j];
      }

    const int m  = tl * 16 + mloc;
    const bool mv = (m < N);

    // dense = X @ Ww + Wb -> f16
#pragma unroll
    for (int t = 0; t < 4; ++t) {
      f32x4 acc = {0.f, 0.f, 0.f, 0.f};
#pragma unroll
      for (int c = 0; c < 4; ++c)
        acc = __builtin_amdgcn_mfma_f32_16x16x16f16(xh[c], wd[t][c], acc, 0, 0, 0);
#pragma unroll
      for (int r = 0; r < 4; ++r) {
        int row = tl * 16 + grp * 4 + r;
        if (row < N)
          dense_h[(size_t)row * D + t * 16 + mloc] = (f16)(acc[r] + wbr[t]);
      }
    }

    // scores: Y = W^T Q^T via MFMA; C-row index == fragment-k index, so the
    // final dot is lane-local (d = t*16 + grp*4 + r  <->  qh[t][r]).
    float dot1 = 0.f, dot2 = 0.f;
#pragma unroll
    for (int t = 0; t < 4; ++t) {
      f32x4 a1 = {0.f, 0.f, 0.f, 0.f}, a2 = {0.f, 0.f, 0.f, 0.f};
#pragma unroll
      for (int c = 0; c < 4; ++c) {
        a1 = __builtin_amdgcn_mfma_f32_16x16x16f16(w1r[t][c], qh[c], a1, 0, 0, 0);
        a2 = __builtin_amdgcn_mfma_f32_16x16x16f16(w2r[t][c], xh[c], a2, 0, 0, 0);
      }
      f32x4 b1v = *(const f32x4*)(W1b + t * 16 + grp * 4);
      f32x4 b2v = *(const f32x4*)(W2b + t * 16 + grp * 4);
#pragma unroll
      for (int r = 0; r < 4; ++r) {
        dot1 += (a1[r] + b1v[r]) * (float)qh[t][r];
        dot2 += (a2[r] + b2v[r]) * (float)xh[t][r];
      }
    }
    dot1 = red4(dot1);
    dot2 = red4(dot2);
    if (grp == 0 && mv) {
      s1[m] = tanhf(dot1);
      s2[m] = tanhf(dot2);
    }
  };

  // ---- 2-deep pipelined grid-stride loop ----
  f32x4 qA[4], iA[4], qB[4], iB[4];
  int tl = wave;
  prefetch(qA, iA, tl);
  while (tl < TILES) {
    prefetch(qB, iB, tl + nwav);
    process(qA, iA, tl);
    tl += nwav;
    if (tl >= TILES) break;
    prefetch(qA, iA, tl + nwav);
    process(qB, iB, tl);
    tl += nwav;
  }
}

// ---------------------------------------------------------------------------
// CSR row pointers from the sorted edge_row array.
// ---------------------------------------------------------------------------
__global__ void rowptr_kernel(const int* __restrict__ erow,
                              int* __restrict__ row_ptr, int E, int N)
{
  int e = blockIdx.x * blockDim.x + threadIdx.x;
  if (e >= E) return;
  int r = erow[e];
  if (e == 0) {
    for (int rr = 0; rr <= r; ++rr) row_ptr[rr] = 0;
  } else {
    int rp = erow[e - 1];
    for (int rr = rp + 1; rr <= r; ++rr) row_ptr[rr] = e;
  }
  if (e == E - 1) {
    for (int rr = r + 1; rr <= N; ++rr) row_ptr[rr] = E;
  }
}

// ---------------------------------------------------------------------------
// Edge-parallel weight kernel: ew[e] = exp(leaky(s1[erow]+s2[ecol])).
// (tanh-bounded logits -> exp without max subtraction is safe; see R3.)
// ---------------------------------------------------------------------------
__global__ void weight_kernel(const int* __restrict__ erow,
                              const int* __restrict__ ecol,
                              const float* __restrict__ s1,
                              const float* __restrict__ s2,
                              float* __restrict__ ew, int E)
{
  int e = blockIdx.x * blockDim.x + threadIdx.x;
  if (e >= E) return;
  float l = s1[erow[e]] + s2[ecol[e]];
  ew[e] = __expf(leaky(l));
}

// ---------------------------------------------------------------------------
// Edge kernel: wave-per-row, 4 edges per VMEM instruction (f16 dense rows),
// ds_bpermute redistribution, pre-normalized weights, fused LN2.
// ---------------------------------------------------------------------------
__global__ __launch_bounds__(256) void edge_kernel(
    const int* __restrict__ row_ptr, const int* __restrict__ ecol,
    const float* __restrict__ ew, const f16* __restrict__ dense_h,
    const float* __restrict__ g2, const float* __restrict__ b2,
    float* __restrict__ out, int N)
{
  const int lane = threadIdx.x & 63;
  const int eg   = lane >> 4;
  const int fl   = lane & 15;
  const int eg4  = eg << 2;
  const int row  = blockIdx.x * (blockDim.x >> 6) + (threadIdx.x >> 6);
  if (row >= N) return;

  const int start = row_ptr[row];
  const int end   = row_ptr[row + 1];
  const int deg   = end - start;

  f32x4 acc = {0.f, 0.f, 0.f, 0.f};

  if (deg > 0 && deg <= 64) {
    int   c = 0;
    float w = 0.f;
    if (lane < deg) {
      c = ecol[start + lane];
      w = ew[start + lane];
    }
    float denom = wave_sum(w);
    float wn = w * __frcp_rn(denom);
    const int nit = (deg + 3) >> 2;
    for (int it = 0; it < nit; ++it) {
      int a = (it << 4) + eg4;
      float wb = bperm_f(a, wn);
      int   cb = bperm_i(a, c);
      f16x4 d = *(const f16x4*)(dense_h + (size_t)cb * D + (fl << 2));
#pragma unroll
      for (int j = 0; j < 4; ++j)
        acc[j] = fmaf((float)d[j], wb, acc[j]);
    }
  } else if (deg > 64) {
    float wl = 0.f;
    for (int b = start + lane; b < end; b += 64) wl += ew[b];
    float inv = __frcp_rn(wave_sum(wl));
    for (int b = start; b < end; b += 64) {
      int nb = min(64, end - b);
      int   c = 0;
      float wn = 0.f;
      if (lane < nb) {
        c = ecol[b + lane];
        wn = ew[b + lane] * inv;
      }
      const int nit = (nb + 3) >> 2;
      for (int it = 0; it < nit; ++it) {
        int a = (it << 4) + eg4;
        float wb = bperm_f(a, wn);
        int   cb = bperm_i(a, c);
        f16x4 d = *(const f16x4*)(dense_h + (size_t)cb * D + (fl << 2));
#pragma unroll
        for (int j = 0; j < 4; ++j)
          acc[j] = fmaf((float)d[j], wb, acc[j]);
      }
    }
  }

#pragma unroll
  for (int j = 0; j < 4; ++j) {
    acc[j] += __shfl_xor(acc[j], 16, 64);
    acc[j] += __shfl_xor(acc[j], 32, 64);
  }

  float s = 0.f, t = 0.f;
#pragma unroll
  for (int j = 0; j < 4; ++j) {
    s += acc[j];
    t += acc[j] * acc[j];
  }
#pragma unroll
  for (int m = 8; m > 0; m >>= 1) {
    s += __shfl_xor(s, m, 64);
    t += __shfl_xor(t, m, 64);
  }
  float mu  = s * (1.f / D);
  float var = fmaxf(t * (1.f / D) - mu * mu, 0.f);
  float rs  = rsqrtf(var + EPS);

  if (eg == 0) {
    f32x4 gv = *(const f32x4*)(g2 + (fl << 2));
    f32x4 bv = *(const f32x4*)(b2 + (fl << 2));
    f32x4 o;
#pragma unroll
    for (int j = 0; j < 4; ++j)
      o[j] = (acc[j] - mu) * rs * gv[j] + bv[j];
    *(f32x4*)(out + (size_t)row * D + (fl << 2)) = o;
  }
}

// ---------------------------------------------------------------------------
extern "C" void kernel_launch(void* const* d_in, const int* in_sizes, int n_in,
                              void* d_out, int out_size, void* d_ws, size_t ws_size,
                              hipStream_t stream)
{
  const float* query  = (const float*)d_in[0];
  const float* input_ = (const float*)d_in[1];
  const int*   erow   = (const int*)d_in[2];
  const int*   ecol   = (const int*)d_in[3];
  const float* Ww     = (const float*)d_in[4];
  const float* Wb     = (const float*)d_in[5];
  const float* W1w    = (const float*)d_in[6];
  const float* W1b    = (const float*)d_in[7];
  const float* W2w    = (const float*)d_in[8];
  const float* W2b    = (const float*)d_in[9];
  const float* g1     = (const float*)d_in[10];
  const float* b1     = (const float*)d_in[11];
  const float* g2     = (const float*)d_in[12];
  const float* b2     = (const float*)d_in[13];

  const int N = in_sizes[0] / D;
  const int E = in_sizes[2];
  float* out = (float*)d_out;

  // ws layout: dense_h f16[N*D] | s1[N] | s2[N] | row_ptr[N+1] | ew[E] | wt
  char* ws = (char*)d_ws;
  f16*   dense_h = (f16*)ws;
  float* s1      = (float*)(ws + (size_t)N * D * sizeof(f16));
  float* s2      = s1 + N;
  int*   row_ptr = (int*)(s2 + N);
  float* ew      = (float*)(row_ptr + N + 1);
  uintptr_t wtp  = (uintptr_t)(ew + E);
  wtp = (wtp + 15) & ~(uintptr_t)15;
  f16* wt = (f16*)wtp;

  wprep_kernel<<<(3 * 4096 + 255) / 256, 256, 0, stream>>>(Ww, W1w, W2w, wt);
  node_kernel<<<512, 256, 0, stream>>>(query, input_, wt, Wb, W1b,
                                       W2b, g1, b1, dense_h, s1, s2, N);
  rowptr_kernel<<<(E + 255) / 256, 256, 0, stream>>>(erow, row_ptr, E, N);
  weight_kernel<<<(E + 255) / 256, 256, 0, stream>>>(erow, ecol, s1, s2, ew, E);
  edge_kernel<<<(N + 3) / 4, 256, 0, stream>>>(row_ptr, ecol, ew, dense_h,
                                               g2, b2, out, N);
}

// Round 7
// 91.771 us; speedup vs baseline: 3.1860x; 1.0801x over previous
//
#include <hip/hip_runtime.h>
#include <math.h>

#define D 64
#define EPS 1e-6f
#define SLOPE 0.2f

typedef _Float16 f16;
typedef _Float16 f16x4 __attribute__((ext_vector_type(4)));
typedef float f32x4 __attribute__((ext_vector_type(4)));

__device__ __forceinline__ float wave_sum(float v) {
#pragma unroll
  for (int m = 32; m > 0; m >>= 1) v += __shfl_xor(v, m, 64);
  return v;
}
__device__ __forceinline__ float red4(float v) {
  v += __shfl_xor(v, 16, 64);
  v += __shfl_xor(v, 32, 64);
  return v;
}
__device__ __forceinline__ float leaky(float l) {
  return (l > 0.f) ? l : SLOPE * l;
}
__device__ __forceinline__ float bperm_f(int byte_addr, float v) {
  return __int_as_float(
      __builtin_amdgcn_ds_bpermute(byte_addr, __float_as_int(v)));
}
__device__ __forceinline__ int bperm_i(int byte_addr, int v) {
  return __builtin_amdgcn_ds_bpermute(byte_addr, v);
}

// ---------------------------------------------------------------------------
// W prep -> FRAGMENT-MAJOR f16 layout (see R5 notes).
// ---------------------------------------------------------------------------
__global__ void wprep_kernel(const float* __restrict__ Ww,
                             const float* __restrict__ W1w,
                             const float* __restrict__ W2w,
                             f16* __restrict__ wt)
{
  int i = blockIdx.x * blockDim.x + threadIdx.x;
  if (i >= 3 * 4096) return;
  int mat = i >> 12, idx = i & 4095;
  int n = idx >> 6, k = idx & 63;
  const float* src = (mat == 0) ? Ww : (mat == 1) ? W1w : W2w;
  int t = n >> 4, mloc = n & 15;
  int c = k >> 4, grp = (k >> 2) & 3, j = k & 3;
  int frag = mat * 16 + t * 4 + c;
  int lane = grp * 16 + mloc;
  wt[(frag << 8) + (lane << 2) + j] = (f16)src[k * 64 + n];
}

// ---------------------------------------------------------------------------
// Node kernel: weights in VGPRs, grid-stride 16-node tiles, 2-deep prefetch.
// (unchanged from R5 — measured ~20us, off the hot list)
// ---------------------------------------------------------------------------
__global__ __launch_bounds__(256, 2) void node_kernel(
    const float* __restrict__ query, const float* __restrict__ input_,
    const f16* __restrict__ wt,
    const float* __restrict__ Wb,  const float* __restrict__ W1b,
    const float* __restrict__ W2b,
    const float* __restrict__ g1,  const float* __restrict__ b1,
    f16* __restrict__ dense_h, float* __restrict__ s1, float* __restrict__ s2,
    int N)
{
  const int lane = threadIdx.x & 63;
  const int grp  = lane >> 4;
  const int mloc = lane & 15;
  const int wave  = blockIdx.x * (blockDim.x >> 6) + (threadIdx.x >> 6);
  const int nwav  = gridDim.x * (blockDim.x >> 6);
  const int TILES = (N + 15) >> 4;

  f16x4 wd[4][4], w1r[4][4], w2r[4][4];
#pragma unroll
  for (int t = 0; t < 4; ++t)
#pragma unroll
    for (int c = 0; c < 4; ++c) {
      int f = t * 4 + c;
      wd[t][c]  = *(const f16x4*)(wt + ((f)      << 8) + (lane << 2));
      w1r[t][c] = *(const f16x4*)(wt + ((16 + f) << 8) + (lane << 2));
      w2r[t][c] = *(const f16x4*)(wt + ((32 + f) << 8) + (lane << 2));
    }
  f32x4 gk[4], bk[4];
#pragma unroll
  for (int c = 0; c < 4; ++c) {
    gk[c] = *(const f32x4*)(g1 + c * 16 + grp * 4);
    bk[c] = *(const f32x4*)(b1 + c * 16 + grp * 4);
  }
  float wbr[4];
#pragma unroll
  for (int t = 0; t < 4; ++t) wbr[t] = Wb[t * 16 + mloc];

  auto prefetch = [&](f32x4* QB, f32x4* IB, int tl) {
    int m = tl * 16 + mloc;
    bool v = (tl < TILES) && (m < N);
    size_t b = (size_t)m * D;
#pragma unroll
    for (int c = 0; c < 4; ++c) {
      int k0 = c * 16 + grp * 4;
      if (v) {
        QB[c] = *(const f32x4*)(query + b + k0);
        IB[c] = *(const f32x4*)(input_ + b + k0);
      } else {
        QB[c] = (f32x4){0.f, 0.f, 0.f, 0.f};
        IB[c] = (f32x4){0.f, 0.f, 0.f, 0.f};
      }
    }
  };

  auto process = [&](f32x4* QB, f32x4* IB, int tl) {
    float s = 0.f;
#pragma unroll
    for (int c = 0; c < 4; ++c)
#pragma unroll
      for (int j = 0; j < 4; ++j) s += IB[c][j];
    s = red4(s);
    float mu = s * (1.f / D);
    float v2 = 0.f;
#pragma unroll
    for (int c = 0; c < 4; ++c)
#pragma unroll
      for (int j = 0; j < 4; ++j) {
        float d = IB[c][j] - mu;
        v2 += d * d;
      }
    v2 = red4(v2);
    float rs = rsqrtf(v2 * (1.f / D) + EPS);

    f16x4 xh[4], qh[4];
#pragma unroll
    for (int c = 0; c < 4; ++c)
#pragma unroll
      for (int j = 0; j < 4; ++j) {
        xh[c][j] = (f16)((IB[c][j] - mu) * rs * gk[c][j] + bk[c][j]);
        qh[c][j] = (f16)QB[c][j];
      }

    const int m  = tl * 16 + mloc;
    const bool mv = (m < N);

#pragma unroll
    for (int t = 0; t < 4; ++t) {
      f32x4 acc = {0.f, 0.f, 0.f, 0.f};
#pragma unroll
      for (int c = 0; c < 4; ++c)
        acc = __builtin_amdgcn_mfma_f32_16x16x16f16(xh[c], wd[t][c], acc, 0, 0, 0);
#pragma unroll
      for (int r = 0; r < 4; ++r) {
        int row = tl * 16 + grp * 4 + r;
        if (row < N)
          dense_h[(size_t)row * D + t * 16 + mloc] = (f16)(acc[r] + wbr[t]);
      }
    }

    float dot1 = 0.f, dot2 = 0.f;
#pragma unroll
    for (int t = 0; t < 4; ++t) {
      f32x4 a1 = {0.f, 0.f, 0.f, 0.f}, a2 = {0.f, 0.f, 0.f, 0.f};
#pragma unroll
      for (int c = 0; c < 4; ++c) {
        a1 = __builtin_amdgcn_mfma_f32_16x16x16f16(w1r[t][c], qh[c], a1, 0, 0, 0);
        a2 = __builtin_amdgcn_mfma_f32_16x16x16f16(w2r[t][c], xh[c], a2, 0, 0, 0);
      }
      f32x4 b1v = *(const f32x4*)(W1b + t * 16 + grp * 4);
      f32x4 b2v = *(const f32x4*)(W2b + t * 16 + grp * 4);
#pragma unroll
      for (int r = 0; r < 4; ++r) {
        dot1 += (a1[r] + b1v[r]) * (float)qh[t][r];
        dot2 += (a2[r] + b2v[r]) * (float)xh[t][r];
      }
    }
    dot1 = red4(dot1);
    dot2 = red4(dot2);
    if (grp == 0 && mv) {
      s1[m] = tanhf(dot1);
      s2[m] = tanhf(dot2);
    }
  };

  f32x4 qA[4], iA[4], qB[4], iB[4];
  int tl = wave;
  prefetch(qA, iA, tl);
  while (tl < TILES) {
    prefetch(qB, iB, tl + nwav);
    process(qA, iA, tl);
    tl += nwav;
    if (tl >= TILES) break;
    prefetch(qA, iA, tl + nwav);
    process(qB, iB, tl);
    tl += nwav;
  }
}

// ---------------------------------------------------------------------------
// prep_kernel = rowptr + edge-weight fused (same E-thread grid).
// cw[e] = (col, f32bits(exp(leaky(s1[row]+s2[col]))))  — one 8B load in edge.
// ---------------------------------------------------------------------------
__global__ void prep_kernel(const int* __restrict__ erow,
                            const int* __restrict__ ecol,
                            const float* __restrict__ s1,
                            const float* __restrict__ s2,
                            int* __restrict__ row_ptr, int2* __restrict__ cw,
                            int E, int N)
{
  int e = blockIdx.x * blockDim.x + threadIdx.x;
  if (e >= E) return;
  int r = erow[e];
  int c = ecol[e];
  float w = __expf(leaky(s1[r] + s2[c]));
  cw[e] = make_int2(c, __float_as_int(w));
  if (e == 0) {
    for (int rr = 0; rr <= r; ++rr) row_ptr[rr] = 0;
  } else {
    int rp = erow[e - 1];
    for (int rr = rp + 1; rr <= r; ++rr) row_ptr[rr] = e;
  }
  if (e == E - 1) {
    for (int rr = r + 1; rr <= N; ++rr) row_ptr[rr] = E;
  }
}

// ---------------------------------------------------------------------------
// Edge kernel v3: TWO rows per wave, fully interleaved independent chains
// (doubles in-flight VMEM/DS per wave; all branches wave-uniform).
// Per iteration each of the 4 sub-groups loads one edge's f16 dense row
// (8B/lane); rows' (col,wn) redistributed via ds_bpermute.  Epilogue: eg==0
// lanes store row0, eg==1 lanes store row1 (post-reduce values are wave-wide).
// ---------------------------------------------------------------------------
__global__ __launch_bounds__(256) void edge_kernel(
    const int* __restrict__ row_ptr, const int2* __restrict__ cw,
    const f16* __restrict__ dense_h,
    const float* __restrict__ g2, const float* __restrict__ b2,
    float* __restrict__ out, int N)
{
  const int lane = threadIdx.x & 63;
  const int eg   = lane >> 4;
  const int fl   = lane & 15;
  const int eg4  = eg << 2;
  const int wv   = blockIdx.x * (blockDim.x >> 6) + (threadIdx.x >> 6);
  const int r0   = wv << 1;
  const int r1   = r0 + 1;
  if (r0 >= N) return;

  const int s0 = row_ptr[r0];
  const int e0 = row_ptr[r0 + 1];
  const int s1r = e0;                       // rows are contiguous in CSR
  const int e1 = (r1 < N) ? row_ptr[r1 + 1] : e0;
  const int d0 = e0 - s0;
  const int d1 = e1 - s1r;

  f32x4 A0 = {0.f, 0.f, 0.f, 0.f}, A1 = {0.f, 0.f, 0.f, 0.f};

  if (d0 <= 64 && d1 <= 64) {
    // ---- fast path (covers ~all rows at mean deg 16) ----
    int c0 = 0, c1 = 0;
    float w0 = 0.f, w1 = 0.f;
    if (lane < d0) {
      int2 p = cw[s0 + lane];
      c0 = p.x; w0 = __int_as_float(p.y);
    }
    if (lane < d1) {
      int2 p = cw[s1r + lane];
      c1 = p.x; w1 = __int_as_float(p.y);
    }
    float t0 = w0, t1 = w1;
#pragma unroll
    for (int m = 32; m > 0; m >>= 1) {
      t0 += __shfl_xor(t0, m, 64);
      t1 += __shfl_xor(t1, m, 64);
    }
    float wn0 = w0 * __frcp_rn(t0);
    float wn1 = w1 * __frcp_rn(t1);
    const int n0 = (d0 + 3) >> 2;
    const int n1 = (d1 + 3) >> 2;
    const int nit = max(n0, n1);
    for (int it = 0; it < nit; ++it) {
      int a = (it << 4) + eg4;
      float wb0, wb1;
      f16x4 v0, v1;
      bool h0 = (it < n0), h1 = (it < n1);
      if (h0) {
        wb0 = bperm_f(a, wn0);
        int cb = bperm_i(a, c0);
        v0 = *(const f16x4*)(dense_h + (size_t)cb * D + (fl << 2));
      }
      if (h1) {
        wb1 = bperm_f(a, wn1);
        int cb = bperm_i(a, c1);
        v1 = *(const f16x4*)(dense_h + (size_t)cb * D + (fl << 2));
      }
      if (h0) {
#pragma unroll
        for (int j = 0; j < 4; ++j) A0[j] = fmaf((float)v0[j], wb0, A0[j]);
      }
      if (h1) {
#pragma unroll
        for (int j = 0; j < 4; ++j) A1[j] = fmaf((float)v1[j], wb1, A1[j]);
      }
    }
  } else {
    // ---- generic path (deg > 64) ----
    auto rowacc = [&](int st, int en, f32x4& A) {
      if (en <= st) return;
      float wl = 0.f;
      for (int b = st + lane; b < en; b += 64)
        wl += __int_as_float(cw[b].y);
      float inv = __frcp_rn(wave_sum(wl));
      for (int b = st; b < en; b += 64) {
        int nb = min(64, en - b);
        int c = 0; float wn = 0.f;
        if (lane < nb) {
          int2 p = cw[b + lane];
          c = p.x; wn = __int_as_float(p.y) * inv;
        }
        int nit = (nb + 3) >> 2;
        for (int it = 0; it < nit; ++it) {
          int a = (it << 4) + eg4;
          float wb = bperm_f(a, wn);
          int   cb = bperm_i(a, c);
          f16x4 d = *(const f16x4*)(dense_h + (size_t)cb * D + (fl << 2));
#pragma unroll
          for (int j = 0; j < 4; ++j) A[j] = fmaf((float)d[j], wb, A[j]);
        }
      }
    };
    rowacc(s0, e0, A0);
    rowacc(s1r, e1, A1);
  }

  // ---- cross-group reduce (interleaved) ----
#pragma unroll
  for (int j = 0; j < 4; ++j) {
    A0[j] += __shfl_xor(A0[j], 16, 64);
    A1[j] += __shfl_xor(A1[j], 16, 64);
    A0[j] += __shfl_xor(A0[j], 32, 64);
    A1[j] += __shfl_xor(A1[j], 32, 64);
  }

  // ---- LN2 stats for both rows (interleaved 16-lane reduce) ----
  float sa0 = 0.f, sq0 = 0.f, sa1 = 0.f, sq1 = 0.f;
#pragma unroll
  for (int j = 0; j < 4; ++j) {
    sa0 += A0[j]; sq0 += A0[j] * A0[j];
    sa1 += A1[j]; sq1 += A1[j] * A1[j];
  }
#pragma unroll
  for (int m = 8; m > 0; m >>= 1) {
    sa0 += __shfl_xor(sa0, m, 64);
    sq0 += __shfl_xor(sq0, m, 64);
    sa1 += __shfl_xor(sa1, m, 64);
    sq1 += __shfl_xor(sq1, m, 64);
  }

  f32x4 gv = *(const f32x4*)(g2 + (fl << 2));
  f32x4 bv = *(const f32x4*)(b2 + (fl << 2));

  if (eg == 0) {
    float mu  = sa0 * (1.f / D);
    float var = fmaxf(sq0 * (1.f / D) - mu * mu, 0.f);
    float rs  = rsqrtf(var + EPS);
    f32x4 o;
#pragma unroll
    for (int j = 0; j < 4; ++j) o[j] = (A0[j] - mu) * rs * gv[j] + bv[j];
    *(f32x4*)(out + (size_t)r0 * D + (fl << 2)) = o;
  } else if (eg == 1 && r1 < N) {
    float mu  = sa1 * (1.f / D);
    float var = fmaxf(sq1 * (1.f / D) - mu * mu, 0.f);
    float rs  = rsqrtf(var + EPS);
    f32x4 o;
#pragma unroll
    for (int j = 0; j < 4; ++j) o[j] = (A1[j] - mu) * rs * gv[j] + bv[j];
    *(f32x4*)(out + (size_t)r1 * D + (fl << 2)) = o;
  }
}

// ---------------------------------------------------------------------------
extern "C" void kernel_launch(void* const* d_in, const int* in_sizes, int n_in,
                              void* d_out, int out_size, void* d_ws, size_t ws_size,
                              hipStream_t stream)
{
  const float* query  = (const float*)d_in[0];
  const float* input_ = (const float*)d_in[1];
  const int*   erow   = (const int*)d_in[2];
  const int*   ecol   = (const int*)d_in[3];
  const float* Ww     = (const float*)d_in[4];
  const float* Wb     = (const float*)d_in[5];
  const float* W1w    = (const float*)d_in[6];
  const float* W1b    = (const float*)d_in[7];
  const float* W2w    = (const float*)d_in[8];
  const float* W2b    = (const float*)d_in[9];
  const float* g1     = (const float*)d_in[10];
  const float* b1     = (const float*)d_in[11];
  const float* g2     = (const float*)d_in[12];
  const float* b2     = (const float*)d_in[13];

  const int N = in_sizes[0] / D;
  const int E = in_sizes[2];
  float* out = (float*)d_out;

  // ws: dense_h f16[N*D] | s1[N] | s2[N] | row_ptr[N+1] | cw int2[E] | wt f16
  char* ws = (char*)d_ws;
  f16*   dense_h = (f16*)ws;
  float* s1      = (float*)(ws + (size_t)N * D * sizeof(f16));
  float* s2      = s1 + N;
  int*   row_ptr = (int*)(s2 + N);
  uintptr_t cwp  = (uintptr_t)(row_ptr + N + 1);
  cwp = (cwp + 7) & ~(uintptr_t)7;
  int2* cw = (int2*)cwp;
  uintptr_t wtp = (uintptr_t)(cw + E);
  wtp = (wtp + 15) & ~(uintptr_t)15;
  f16* wt = (f16*)wtp;

  wprep_kernel<<<(3 * 4096 + 255) / 256, 256, 0, stream>>>(Ww, W1w, W2w, wt);
  node_kernel<<<512, 256, 0, stream>>>(query, input_, wt, Wb, W1b,
                                       W2b, g1, b1, dense_h, s1, s2, N);
  prep_kernel<<<(E + 255) / 256, 256, 0, stream>>>(erow, ecol, s1, s2,
                                                   row_ptr, cw, E, N);
  edge_kernel<<<((N + 1) / 2 + 3) / 4, 256, 0, stream>>>(row_ptr, cw, dense_h,
                                                         g2, b2, out, N);
}

// Round 8
// 87.997 us; speedup vs baseline: 3.3227x; 1.0429x over previous
//
#include <hip/hip_runtime.h>
#include <math.h>

#define D 64
#define EPS 1e-6f
#define SLOPE 0.2f

typedef _Float16 f16;
typedef _Float16 f16x4 __attribute__((ext_vector_type(4)));
typedef float f32x4 __attribute__((ext_vector_type(4)));

__device__ __forceinline__ float red4(float v) {
  v += __shfl_xor(v, 16, 64);
  v += __shfl_xor(v, 32, 64);
  return v;
}
__device__ __forceinline__ float leaky(float l) {
  return (l > 0.f) ? l : SLOPE * l;
}
__device__ __forceinline__ float bperm_f(int byte_addr, float v) {
  return __int_as_float(
      __builtin_amdgcn_ds_bpermute(byte_addr, __float_as_int(v)));
}
__device__ __forceinline__ int bperm_i(int byte_addr, int v) {
  return __builtin_amdgcn_ds_bpermute(byte_addr, v);
}

// ---------------------------------------------------------------------------
// W prep -> FRAGMENT-MAJOR f16 layout (see R5 notes).
// ---------------------------------------------------------------------------
__global__ void wprep_kernel(const float* __restrict__ Ww,
                             const float* __restrict__ W1w,
                             const float* __restrict__ W2w,
                             f16* __restrict__ wt)
{
  int i = blockIdx.x * blockDim.x + threadIdx.x;
  if (i >= 3 * 4096) return;
  int mat = i >> 12, idx = i & 4095;
  int n = idx >> 6, k = idx & 63;
  const float* src = (mat == 0) ? Ww : (mat == 1) ? W1w : W2w;
  int t = n >> 4, mloc = n & 15;
  int c = k >> 4, grp = (k >> 2) & 3, j = k & 3;
  int frag = mat * 16 + t * 4 + c;
  int lane = grp * 16 + mloc;
  wt[(frag << 8) + (lane << 2) + j] = (f16)src[k * 64 + n];
}

// ---------------------------------------------------------------------------
// Node kernel: weights in VGPRs, grid-stride 16-node tiles, 2-deep prefetch.
// (unchanged from R5 — ~20us)
// ---------------------------------------------------------------------------
__global__ __launch_bounds__(256, 2) void node_kernel(
    const float* __restrict__ query, const float* __restrict__ input_,
    const f16* __restrict__ wt,
    const float* __restrict__ Wb,  const float* __restrict__ W1b,
    const float* __restrict__ W2b,
    const float* __restrict__ g1,  const float* __restrict__ b1,
    f16* __restrict__ dense_h, float* __restrict__ s1, float* __restrict__ s2,
    int N)
{
  const int lane = threadIdx.x & 63;
  const int grp  = lane >> 4;
  const int mloc = lane & 15;
  const int wave  = blockIdx.x * (blockDim.x >> 6) + (threadIdx.x >> 6);
  const int nwav  = gridDim.x * (blockDim.x >> 6);
  const int TILES = (N + 15) >> 4;

  f16x4 wd[4][4], w1r[4][4], w2r[4][4];
#pragma unroll
  for (int t = 0; t < 4; ++t)
#pragma unroll
    for (int c = 0; c < 4; ++c) {
      int f = t * 4 + c;
      wd[t][c]  = *(const f16x4*)(wt + ((f)      << 8) + (lane << 2));
      w1r[t][c] = *(const f16x4*)(wt + ((16 + f) << 8) + (lane << 2));
      w2r[t][c] = *(const f16x4*)(wt + ((32 + f) << 8) + (lane << 2));
    }
  f32x4 gk[4], bk[4];
#pragma unroll
  for (int c = 0; c < 4; ++c) {
    gk[c] = *(const f32x4*)(g1 + c * 16 + grp * 4);
    bk[c] = *(const f32x4*)(b1 + c * 16 + grp * 4);
  }
  float wbr[4];
#pragma unroll
  for (int t = 0; t < 4; ++t) wbr[t] = Wb[t * 16 + mloc];

  auto prefetch = [&](f32x4* QB, f32x4* IB, int tl) {
    int m = tl * 16 + mloc;
    bool v = (tl < TILES) && (m < N);
    size_t b = (size_t)m * D;
#pragma unroll
    for (int c = 0; c < 4; ++c) {
      int k0 = c * 16 + grp * 4;
      if (v) {
        QB[c] = *(const f32x4*)(query + b + k0);
        IB[c] = *(const f32x4*)(input_ + b + k0);
      } else {
        QB[c] = (f32x4){0.f, 0.f, 0.f, 0.f};
        IB[c] = (f32x4){0.f, 0.f, 0.f, 0.f};
      }
    }
  };

  auto process = [&](f32x4* QB, f32x4* IB, int tl) {
    float s = 0.f;
#pragma unroll
    for (int c = 0; c < 4; ++c)
#pragma unroll
      for (int j = 0; j < 4; ++j) s += IB[c][j];
    s = red4(s);
    float mu = s * (1.f / D);
    float v2 = 0.f;
#pragma unroll
    for (int c = 0; c < 4; ++c)
#pragma unroll
      for (int j = 0; j < 4; ++j) {
        float d = IB[c][j] - mu;
        v2 += d * d;
      }
    v2 = red4(v2);
    float rs = rsqrtf(v2 * (1.f / D) + EPS);

    f16x4 xh[4], qh[4];
#pragma unroll
    for (int c = 0; c < 4; ++c)
#pragma unroll
      for (int j = 0; j < 4; ++j) {
        xh[c][j] = (f16)((IB[c][j] - mu) * rs * gk[c][j] + bk[c][j]);
        qh[c][j] = (f16)QB[c][j];
      }

    const int m  = tl * 16 + mloc;
    const bool mv = (m < N);

#pragma unroll
    for (int t = 0; t < 4; ++t) {
      f32x4 acc = {0.f, 0.f, 0.f, 0.f};
#pragma unroll
      for (int c = 0; c < 4; ++c)
        acc = __builtin_amdgcn_mfma_f32_16x16x16f16(xh[c], wd[t][c], acc, 0, 0, 0);
#pragma unroll
      for (int r = 0; r < 4; ++r) {
        int row = tl * 16 + grp * 4 + r;
        if (row < N)
          dense_h[(size_t)row * D + t * 16 + mloc] = (f16)(acc[r] + wbr[t]);
      }
    }

    float dot1 = 0.f, dot2 = 0.f;
#pragma unroll
    for (int t = 0; t < 4; ++t) {
      f32x4 a1 = {0.f, 0.f, 0.f, 0.f}, a2 = {0.f, 0.f, 0.f, 0.f};
#pragma unroll
      for (int c = 0; c < 4; ++c) {
        a1 = __builtin_amdgcn_mfma_f32_16x16x16f16(w1r[t][c], qh[c], a1, 0, 0, 0);
        a2 = __builtin_amdgcn_mfma_f32_16x16x16f16(w2r[t][c], xh[c], a2, 0, 0, 0);
      }
      f32x4 b1v = *(const f32x4*)(W1b + t * 16 + grp * 4);
      f32x4 b2v = *(const f32x4*)(W2b + t * 16 + grp * 4);
#pragma unroll
      for (int r = 0; r < 4; ++r) {
        dot1 += (a1[r] + b1v[r]) * (float)qh[t][r];
        dot2 += (a2[r] + b2v[r]) * (float)xh[t][r];
      }
    }
    dot1 = red4(dot1);
    dot2 = red4(dot2);
    if (grp == 0 && mv) {
      s1[m] = tanhf(dot1);
      s2[m] = tanhf(dot2);
    }
  };

  f32x4 qA[4], iA[4], qB[4], iB[4];
  int tl = wave;
  prefetch(qA, iA, tl);
  while (tl < TILES) {
    prefetch(qB, iB, tl + nwav);
    process(qA, iA, tl);
    tl += nwav;
    if (tl >= TILES) break;
    prefetch(qA, iA, tl + nwav);
    process(qB, iB, tl);
    tl += nwav;
  }
}

// ---------------------------------------------------------------------------
// CSR row pointers from the sorted edge_row array.
// ---------------------------------------------------------------------------
__global__ void rowptr_kernel(const int* __restrict__ erow,
                              int* __restrict__ row_ptr, int E, int N)
{
  int e = blockIdx.x * blockDim.x + threadIdx.x;
  if (e >= E) return;
  int r = erow[e];
  if (e == 0) {
    for (int rr = 0; rr <= r; ++rr) row_ptr[rr] = 0;
  } else {
    int rp = erow[e - 1];
    for (int rr = rp + 1; rr <= r; ++rr) row_ptr[rr] = e;
  }
  if (e == E - 1) {
    for (int rr = r + 1; rr <= N; ++rr) row_ptr[rr] = E;
  }
}

// ---------------------------------------------------------------------------
// Edge kernel v4: FOUR rows per wave, weights computed inline
// (w = exp(leaky(s1[row]+s2[col])); s2 gather is L2-resident, lane-parallel),
// and NO softmax normalization: LN2 is invariant to positive row scaling
// (effect limited to EPS/S^2 vs EPS inside rsqrt, ~5e-5 relative).
// Per iteration the 4 sub-groups each load one edge's f16 dense row (8B/lane)
// per row-chain; (col,w) redistributed via ds_bpermute.  All 4 chains
// independent -> ~16 gathers in flight per wave.
// ---------------------------------------------------------------------------
__global__ __launch_bounds__(256) void edge_kernel(
    const int* __restrict__ row_ptr, const int* __restrict__ ecol,
    const float* __restrict__ s1v, const float* __restrict__ s2v,
    const f16* __restrict__ dense_h,
    const float* __restrict__ g2, const float* __restrict__ b2,
    float* __restrict__ out, int N)
{
  const int lane = threadIdx.x & 63;
  const int eg   = lane >> 4;
  const int fl   = lane & 15;
  const int eg4  = eg << 2;
  const int wv   = blockIdx.x * (blockDim.x >> 6) + (threadIdx.x >> 6);
  const int r0   = wv << 2;
  if (r0 >= N) return;

  // CSR bounds for the 4 rows (contiguous): p[j] = row_ptr[min(r0+j, N)]
  int p[5];
#pragma unroll
  for (int j = 0; j < 5; ++j) p[j] = row_ptr[min(r0 + j, N)];
  int dg[4];
#pragma unroll
  for (int r = 0; r < 4; ++r) dg[r] = p[r + 1] - p[r];

  float s1r[4];
#pragma unroll
  for (int r = 0; r < 4; ++r) s1r[r] = s1v[min(r0 + r, N - 1)];

  f32x4 A[4];
#pragma unroll
  for (int r = 0; r < 4; ++r) A[r] = (f32x4){0.f, 0.f, 0.f, 0.f};

  const bool fast = (dg[0] <= 64) & (dg[1] <= 64) & (dg[2] <= 64) & (dg[3] <= 64);

  if (fast) {
    // ---- fast path (mean deg 16; covers ~all rows) ----
    int   c[4];
    float w[4];
#pragma unroll
    for (int r = 0; r < 4; ++r) {
      c[r] = 0;
      if (lane < dg[r]) c[r] = ecol[p[r] + lane];
    }
#pragma unroll
    for (int r = 0; r < 4; ++r) {
      float s2g = 0.f;
      if (lane < dg[r]) s2g = s2v[c[r]];
      w[r] = (lane < dg[r]) ? __expf(leaky(s1r[r] + s2g)) : 0.f;
    }
    int nit[4];
#pragma unroll
    for (int r = 0; r < 4; ++r) nit[r] = (dg[r] + 3) >> 2;
    const int nmax = max(max(nit[0], nit[1]), max(nit[2], nit[3]));

    for (int it = 0; it < nmax; ++it) {
      int a = (it << 4) + eg4;
      float wb[4];
      f16x4 v[4];
#pragma unroll
      for (int r = 0; r < 4; ++r) {
        if (it < nit[r]) {
          wb[r] = bperm_f(a, w[r]);
          int cb = bperm_i(a, c[r]);
          v[r] = *(const f16x4*)(dense_h + (size_t)cb * D + (fl << 2));
        }
      }
#pragma unroll
      for (int r = 0; r < 4; ++r) {
        if (it < nit[r]) {
#pragma unroll
          for (int j = 0; j < 4; ++j)
            A[r][j] = fmaf((float)v[r][j], wb[r], A[r][j]);
        }
      }
    }
  } else {
    // ---- generic path (some deg > 64) ----
    auto rowacc = [&](int st, int en, float s1i, f32x4& Ar) {
      for (int b = st; b < en; b += 64) {
        int nb = min(64, en - b);
        int cc = 0;
        float ww = 0.f;
        if (lane < nb) {
          cc = ecol[b + lane];
          ww = __expf(leaky(s1i + s2v[cc]));
        }
        int nit = (nb + 3) >> 2;
        for (int it = 0; it < nit; ++it) {
          int a = (it << 4) + eg4;
          float wb = bperm_f(a, ww);
          int   cb = bperm_i(a, cc);
          f16x4 d = *(const f16x4*)(dense_h + (size_t)cb * D + (fl << 2));
#pragma unroll
          for (int j = 0; j < 4; ++j)
            Ar[j] = fmaf((float)d[j], wb, Ar[j]);
        }
      }
    };
#pragma unroll
    for (int r = 0; r < 4; ++r) rowacc(p[r], p[r + 1], s1r[r], A[r]);
  }

  // ---- cross-group reduce (4 rows interleaved) ----
#pragma unroll
  for (int j = 0; j < 4; ++j) {
#pragma unroll
    for (int r = 0; r < 4; ++r) A[r][j] += __shfl_xor(A[r][j], 16, 64);
#pragma unroll
    for (int r = 0; r < 4; ++r) A[r][j] += __shfl_xor(A[r][j], 32, 64);
  }

  // ---- LN2 stats (un-normalized input; LN absorbs the softmax denom) ----
  float sa[4], sq[4];
#pragma unroll
  for (int r = 0; r < 4; ++r) {
    sa[r] = 0.f; sq[r] = 0.f;
#pragma unroll
    for (int j = 0; j < 4; ++j) {
      sa[r] += A[r][j];
      sq[r] += A[r][j] * A[r][j];
    }
  }
#pragma unroll
  for (int m = 8; m > 0; m >>= 1) {
#pragma unroll
    for (int r = 0; r < 4; ++r) {
      sa[r] += __shfl_xor(sa[r], m, 64);
      sq[r] += __shfl_xor(sq[r], m, 64);
    }
  }

  f32x4 gv = *(const f32x4*)(g2 + (fl << 2));
  f32x4 bv = *(const f32x4*)(b2 + (fl << 2));

  // sub-group eg stores row eg (post-reduce values are wave-wide); static
  // branches to keep register indexing compile-time (no scratch).
#define STORE_ROW(R)                                                        \
  if (eg == R && r0 + R < N) {                                              \
    float mu  = sa[R] * (1.f / D);                                          \
    float var = fmaxf(sq[R] * (1.f / D) - mu * mu, 0.f);                    \
    float rs  = rsqrtf(var + EPS);                                          \
    f32x4 o;                                                                \
    _Pragma("unroll")                                                       \
    for (int j = 0; j < 4; ++j) o[j] = (A[R][j] - mu) * rs * gv[j] + bv[j]; \
    *(f32x4*)(out + (size_t)(r0 + R) * D + (fl << 2)) = o;                  \
  }
  STORE_ROW(0)
  STORE_ROW(1)
  STORE_ROW(2)
  STORE_ROW(3)
#undef STORE_ROW
}

// ---------------------------------------------------------------------------
extern "C" void kernel_launch(void* const* d_in, const int* in_sizes, int n_in,
                              void* d_out, int out_size, void* d_ws, size_t ws_size,
                              hipStream_t stream)
{
  const float* query  = (const float*)d_in[0];
  const float* input_ = (const float*)d_in[1];
  const int*   erow   = (const int*)d_in[2];
  const int*   ecol   = (const int*)d_in[3];
  const float* Ww     = (const float*)d_in[4];
  const float* Wb     = (const float*)d_in[5];
  const float* W1w    = (const float*)d_in[6];
  const float* W1b    = (const float*)d_in[7];
  const float* W2w    = (const float*)d_in[8];
  const float* W2b    = (const float*)d_in[9];
  const float* g1     = (const float*)d_in[10];
  const float* b1     = (const float*)d_in[11];
  const float* g2     = (const float*)d_in[12];
  const float* b2     = (const float*)d_in[13];

  const int N = in_sizes[0] / D;
  const int E = in_sizes[2];
  float* out = (float*)d_out;

  // ws: dense_h f16[N*D] | s1[N] | s2[N] | row_ptr[N+1] | wt f16
  char* ws = (char*)d_ws;
  f16*   dense_h = (f16*)ws;
  float* s1      = (float*)(ws + (size_t)N * D * sizeof(f16));
  float* s2      = s1 + N;
  int*   row_ptr = (int*)(s2 + N);
  uintptr_t wtp  = (uintptr_t)(row_ptr + N + 1);
  wtp = (wtp + 15) & ~(uintptr_t)15;
  f16* wt = (f16*)wtp;

  wprep_kernel<<<(3 * 4096 + 255) / 256, 256, 0, stream>>>(Ww, W1w, W2w, wt);
  node_kernel<<<512, 256, 0, stream>>>(query, input_, wt, Wb, W1b,
                                       W2b, g1, b1, dense_h, s1, s2, N);
  rowptr_kernel<<<(E + 255) / 256, 256, 0, stream>>>(erow, row_ptr, E, N);
  const int waves = (N + 3) / 4;
  edge_kernel<<<(waves + 3) / 4, 256, 0, stream>>>(row_ptr, ecol, s1, s2,
                                                   dense_h, g2, b2, out, N);
}

// Round 9
// 75.061 us; speedup vs baseline: 3.8953x; 1.1723x over previous
//
#include <hip/hip_runtime.h>
#include <math.h>

#define D 64
#define EPS 1e-6f
#define SLOPE 0.2f

typedef _Float16 f16;
typedef _Float16 f16x4 __attribute__((ext_vector_type(4)));
typedef _Float16 f16x8 __attribute__((ext_vector_type(8)));
typedef float f32x4 __attribute__((ext_vector_type(4)));

__device__ __forceinline__ float red4(float v) {
  v += __shfl_xor(v, 16, 64);
  v += __shfl_xor(v, 32, 64);
  return v;
}
__device__ __forceinline__ float leaky(float l) {
  return (l > 0.f) ? l : SLOPE * l;
}
__device__ __forceinline__ float bperm_f(int byte_addr, float v) {
  return __int_as_float(
      __builtin_amdgcn_ds_bpermute(byte_addr, __float_as_int(v)));
}
__device__ __forceinline__ int bperm_i(int byte_addr, int v) {
  return __builtin_amdgcn_ds_bpermute(byte_addr, v);
}

// ---------------------------------------------------------------------------
// W prep -> FRAGMENT-MAJOR f16 layout (see R5 notes).
// ---------------------------------------------------------------------------
__global__ void wprep_kernel(const float* __restrict__ Ww,
                             const float* __restrict__ W1w,
                             const float* __restrict__ W2w,
                             f16* __restrict__ wt)
{
  int i = blockIdx.x * blockDim.x + threadIdx.x;
  if (i >= 3 * 4096) return;
  int mat = i >> 12, idx = i & 4095;
  int n = idx >> 6, k = idx & 63;
  const float* src = (mat == 0) ? Ww : (mat == 1) ? W1w : W2w;
  int t = n >> 4, mloc = n & 15;
  int c = k >> 4, grp = (k >> 2) & 3, j = k & 3;
  int frag = mat * 16 + t * 4 + c;
  int lane = grp * 16 + mloc;
  wt[(frag << 8) + (lane << 2) + j] = (f16)src[k * 64 + n];
}

// ---------------------------------------------------------------------------
// Node kernel: weights in VGPRs, grid-stride 16-node tiles, 2-deep prefetch.
// (unchanged from R5 — ~20us)
// ---------------------------------------------------------------------------
__global__ __launch_bounds__(256, 2) void node_kernel(
    const float* __restrict__ query, const float* __restrict__ input_,
    const f16* __restrict__ wt,
    const float* __restrict__ Wb,  const float* __restrict__ W1b,
    const float* __restrict__ W2b,
    const float* __restrict__ g1,  const float* __restrict__ b1,
    f16* __restrict__ dense_h, float* __restrict__ s1, float* __restrict__ s2,
    int N)
{
  const int lane = threadIdx.x & 63;
  const int grp  = lane >> 4;
  const int mloc = lane & 15;
  const int wave  = blockIdx.x * (blockDim.x >> 6) + (threadIdx.x >> 6);
  const int nwav  = gridDim.x * (blockDim.x >> 6);
  const int TILES = (N + 15) >> 4;

  f16x4 wd[4][4], w1r[4][4], w2r[4][4];
#pragma unroll
  for (int t = 0; t < 4; ++t)
#pragma unroll
    for (int c = 0; c < 4; ++c) {
      int f = t * 4 + c;
      wd[t][c]  = *(const f16x4*)(wt + ((f)      << 8) + (lane << 2));
      w1r[t][c] = *(const f16x4*)(wt + ((16 + f) << 8) + (lane << 2));
      w2r[t][c] = *(const f16x4*)(wt + ((32 + f) << 8) + (lane << 2));
    }
  f32x4 gk[4], bk[4];
#pragma unroll
  for (int c = 0; c < 4; ++c) {
    gk[c] = *(const f32x4*)(g1 + c * 16 + grp * 4);
    bk[c] = *(const f32x4*)(b1 + c * 16 + grp * 4);
  }
  float wbr[4];
#pragma unroll
  for (int t = 0; t < 4; ++t) wbr[t] = Wb[t * 16 + mloc];

  auto prefetch = [&](f32x4* QB, f32x4* IB, int tl) {
    int m = tl * 16 + mloc;
    bool v = (tl < TILES) && (m < N);
    size_t b = (size_t)m * D;
#pragma unroll
    for (int c = 0; c < 4; ++c) {
      int k0 = c * 16 + grp * 4;
      if (v) {
        QB[c] = *(const f32x4*)(query + b + k0);
        IB[c] = *(const f32x4*)(input_ + b + k0);
      } else {
        QB[c] = (f32x4){0.f, 0.f, 0.f, 0.f};
        IB[c] = (f32x4){0.f, 0.f, 0.f, 0.f};
      }
    }
  };

  auto process = [&](f32x4* QB, f32x4* IB, int tl) {
    float s = 0.f;
#pragma unroll
    for (int c = 0; c < 4; ++c)
#pragma unroll
      for (int j = 0; j < 4; ++j) s += IB[c][j];
    s = red4(s);
    float mu = s * (1.f / D);
    float v2 = 0.f;
#pragma unroll
    for (int c = 0; c < 4; ++c)
#pragma unroll
      for (int j = 0; j < 4; ++j) {
        float d = IB[c][j] - mu;
        v2 += d * d;
      }
    v2 = red4(v2);
    float rs = rsqrtf(v2 * (1.f / D) + EPS);

    f16x4 xh[4], qh[4];
#pragma unroll
    for (int c = 0; c < 4; ++c)
#pragma unroll
      for (int j = 0; j < 4; ++j) {
        xh[c][j] = (f16)((IB[c][j] - mu) * rs * gk[c][j] + bk[c][j]);
        qh[c][j] = (f16)QB[c][j];
      }

    const int m  = tl * 16 + mloc;
    const bool mv = (m < N);

#pragma unroll
    for (int t = 0; t < 4; ++t) {
      f32x4 acc = {0.f, 0.f, 0.f, 0.f};
#pragma unroll
      for (int c = 0; c < 4; ++c)
        acc = __builtin_amdgcn_mfma_f32_16x16x16f16(xh[c], wd[t][c], acc, 0, 0, 0);
#pragma unroll
      for (int r = 0; r < 4; ++r) {
        int row = tl * 16 + grp * 4 + r;
        if (row < N)
          dense_h[(size_t)row * D + t * 16 + mloc] = (f16)(acc[r] + wbr[t]);
      }
    }

    float dot1 = 0.f, dot2 = 0.f;
#pragma unroll
    for (int t = 0; t < 4; ++t) {
      f32x4 a1 = {0.f, 0.f, 0.f, 0.f}, a2 = {0.f, 0.f, 0.f, 0.f};
#pragma unroll
      for (int c = 0; c < 4; ++c) {
        a1 = __builtin_amdgcn_mfma_f32_16x16x16f16(w1r[t][c], qh[c], a1, 0, 0, 0);
        a2 = __builtin_amdgcn_mfma_f32_16x16x16f16(w2r[t][c], xh[c], a2, 0, 0, 0);
      }
      f32x4 b1v = *(const f32x4*)(W1b + t * 16 + grp * 4);
      f32x4 b2v = *(const f32x4*)(W2b + t * 16 + grp * 4);
#pragma unroll
      for (int r = 0; r < 4; ++r) {
        dot1 += (a1[r] + b1v[r]) * (float)qh[t][r];
        dot2 += (a2[r] + b2v[r]) * (float)xh[t][r];
      }
    }
    dot1 = red4(dot1);
    dot2 = red4(dot2);
    if (grp == 0 && mv) {
      s1[m] = tanhf(dot1);
      s2[m] = tanhf(dot2);
    }
  };

  f32x4 qA[4], iA[4], qB[4], iB[4];
  int tl = wave;
  prefetch(qA, iA, tl);
  while (tl < TILES) {
    prefetch(qB, iB, tl + nwav);
    process(qA, iA, tl);
    tl += nwav;
    if (tl >= TILES) break;
    prefetch(qA, iA, tl + nwav);
    process(qB, iB, tl);
    tl += nwav;
  }
}

// ---------------------------------------------------------------------------
// CSR row pointers from the sorted edge_row array.
// ---------------------------------------------------------------------------
__global__ void rowptr_kernel(const int* __restrict__ erow,
                              int* __restrict__ row_ptr, int E, int N)
{
  int e = blockIdx.x * blockDim.x + threadIdx.x;
  if (e >= E) return;
  int r = erow[e];
  if (e == 0) {
    for (int rr = 0; rr <= r; ++rr) row_ptr[rr] = 0;
  } else {
    int rp = erow[e - 1];
    for (int rr = rp + 1; rr <= r; ++rr) row_ptr[rr] = e;
  }
  if (e == E - 1) {
    for (int rr = r + 1; rr <= N; ++rr) row_ptr[rr] = E;
  }
}

// ---------------------------------------------------------------------------
// accum<NIT>: fully-unrolled gather/accumulate engine.  Lane = 8*eg + fl.
// Lower half (eg 0..3) serves row0, upper half row1.  Iteration it pulls
// (w, c) of slot 4*it + (eg&3) of its half via ds_bpermute, then loads that
// edge's f16 dense row as f16x8 (16B/lane, 8 edges per VMEM instruction).
// Compile-time NIT => all bpermutes and gathers issue up front and overlap.
// ---------------------------------------------------------------------------
template <int NIT>
__device__ __forceinline__ void accum(const f16* __restrict__ dense_h,
                                      int eg, int fl, int c, float w,
                                      float* A)
{
#pragma unroll
  for (int it = 0; it < NIT; ++it) {
    int a = (((eg & 4) << 3) + (it << 2) + (eg & 3)) << 2;
    float wb = bperm_f(a, w);
    int   cb = bperm_i(a, c);
    f16x8 v = *(const f16x8*)(dense_h + (size_t)cb * D + (fl << 3));
#pragma unroll
    for (int j = 0; j < 8; ++j)
      A[j] = fmaf((float)v[j], wb, A[j]);
  }
}

// ---------------------------------------------------------------------------
// Edge kernel v5: 2 rows/wave, half-wave slot ownership (<=32 edges/row fast
// path), one gather + one exp covers both rows, unrolled accum engine.
// No softmax denominator (LN2 absorbs positive row scaling; see R8).
// ---------------------------------------------------------------------------
__global__ __launch_bounds__(256) void edge_kernel(
    const int* __restrict__ row_ptr, const int* __restrict__ ecol,
    const float* __restrict__ s1v, const float* __restrict__ s2v,
    const f16* __restrict__ dense_h,
    const float* __restrict__ g2, const float* __restrict__ b2,
    float* __restrict__ out, int N)
{
  const int lane = threadIdx.x & 63;
  const int eg   = lane >> 3;          // 0..7 (edge sub-group)
  const int fl   = lane & 7;           // feature octet 0..7
  const int wv   = blockIdx.x * (blockDim.x >> 6) + (threadIdx.x >> 6);
  const int r0   = wv << 1;
  const int r1   = r0 + 1;
  if (r0 >= N) return;

  const int pa = row_ptr[r0];
  const int pb = row_ptr[r0 + 1];
  const int pc = row_ptr[min(r0 + 2, N)];
  const int d0 = pb - pa;
  const int d1 = (r1 < N) ? (pc - pb) : 0;

  const bool hi  = (lane >= 32);
  const int  sl  = lane & 31;          // slot within the half's row
  const int  dgx = hi ? d1 : d0;
  const int  bse = hi ? pb : pa;
  const float s1x = s1v[hi ? min(r1, N - 1) : r0];

  // one predicated gather pair + one exp covers both rows
  int c = 0;
  if (sl < dgx) c = ecol[bse + sl];
  float w = 0.f;
  if (sl < dgx) w = __expf(leaky(s1x + s2v[c]));

  float A[8] = {0.f, 0.f, 0.f, 0.f, 0.f, 0.f, 0.f, 0.f};
  const int maxd = max(d0, d1);

  if (maxd <= 32) {
    const int nit = (maxd + 3) >> 2;
    if      (nit <= 2) accum<2>(dense_h, eg, fl, c, w, A);
    else if (nit <= 4) accum<4>(dense_h, eg, fl, c, w, A);
    else if (nit <= 6) accum<6>(dense_h, eg, fl, c, w, A);
    else               accum<8>(dense_h, eg, fl, c, w, A);
  } else {
    // ---- rare generic path (deg > 32): full wave per row, 64-slot blocks ----
    float A0[8] = {0.f, 0.f, 0.f, 0.f, 0.f, 0.f, 0.f, 0.f};
    float A1[8] = {0.f, 0.f, 0.f, 0.f, 0.f, 0.f, 0.f, 0.f};
    auto rowacc = [&](int st, int en, float s1i, float* Ar) {
      for (int b = st; b < en; b += 64) {
        int nb = min(64, en - b);
        int cc = 0;
        float ww = 0.f;
        if (lane < nb) {
          cc = ecol[b + lane];
          ww = __expf(leaky(s1i + s2v[cc]));
        }
#pragma unroll
        for (int it = 0; it < 8; ++it) {
          int a = ((it << 3) + eg) << 2;
          float wb = bperm_f(a, ww);
          int   cb = bperm_i(a, cc);
          f16x8 v = *(const f16x8*)(dense_h + (size_t)cb * D + (fl << 3));
#pragma unroll
          for (int j = 0; j < 8; ++j)
            Ar[j] = fmaf((float)v[j], wb, Ar[j]);
        }
      }
    };
    rowacc(pa, pb, s1v[r0], A0);
    if (r1 < N) rowacc(pb, pc, s1v[r1], A1);
#pragma unroll
    for (int j = 0; j < 8; ++j) {
      A0[j] += __shfl_xor(A0[j], 32, 64);
      A1[j] += __shfl_xor(A1[j], 32, 64);
      A[j] = hi ? A1[j] : A0[j];
    }
  }

  // ---- reduce over the 4 sub-groups within each half ----
#pragma unroll
  for (int j = 0; j < 8; ++j) {
    A[j] += __shfl_xor(A[j], 8, 64);
    A[j] += __shfl_xor(A[j], 16, 64);
  }

  // ---- LN2 stats per half (8-lane feature reduce) ----
  float sa = 0.f, sq = 0.f;
#pragma unroll
  for (int j = 0; j < 8; ++j) {
    sa += A[j];
    sq += A[j] * A[j];
  }
#pragma unroll
  for (int m = 4; m > 0; m >>= 1) {
    sa += __shfl_xor(sa, m, 64);
    sq += __shfl_xor(sq, m, 64);
  }
  float mu  = sa * (1.f / D);
  float var = fmaxf(sq * (1.f / D) - mu * mu, 0.f);
  float rs  = rsqrtf(var + EPS);

  f32x4 gv0 = *(const f32x4*)(g2 + (fl << 3));
  f32x4 gv1 = *(const f32x4*)(g2 + (fl << 3) + 4);
  f32x4 bv0 = *(const f32x4*)(b2 + (fl << 3));
  f32x4 bv1 = *(const f32x4*)(b2 + (fl << 3) + 4);

  f32x4 o0, o1;
#pragma unroll
  for (int j = 0; j < 4; ++j) {
    o0[j] = (A[j]     - mu) * rs * gv0[j] + bv0[j];
    o1[j] = (A[j + 4] - mu) * rs * gv1[j] + bv1[j];
  }
  if (eg == 0) {
    *(f32x4*)(out + (size_t)r0 * D + (fl << 3))     = o0;
    *(f32x4*)(out + (size_t)r0 * D + (fl << 3) + 4) = o1;
  } else if (eg == 4 && r1 < N) {
    *(f32x4*)(out + (size_t)r1 * D + (fl << 3))     = o0;
    *(f32x4*)(out + (size_t)r1 * D + (fl << 3) + 4) = o1;
  }
}

// ---------------------------------------------------------------------------
extern "C" void kernel_launch(void* const* d_in, const int* in_sizes, int n_in,
                              void* d_out, int out_size, void* d_ws, size_t ws_size,
                              hipStream_t stream)
{
  const float* query  = (const float*)d_in[0];
  const float* input_ = (const float*)d_in[1];
  const int*   erow   = (const int*)d_in[2];
  const int*   ecol   = (const int*)d_in[3];
  const float* Ww     = (const float*)d_in[4];
  const float* Wb     = (const float*)d_in[5];
  const float* W1w    = (const float*)d_in[6];
  const float* W1b    = (const float*)d_in[7];
  const float* W2w    = (const float*)d_in[8];
  const float* W2b    = (const float*)d_in[9];
  const float* g1     = (const float*)d_in[10];
  const float* b1     = (const float*)d_in[11];
  const float* g2     = (const float*)d_in[12];
  const float* b2     = (const float*)d_in[13];

  const int N = in_sizes[0] / D;
  const int E = in_sizes[2];
  float* out = (float*)d_out;

  // ws: dense_h f16[N*D] | s1[N] | s2[N] | row_ptr[N+1] | wt f16
  char* ws = (char*)d_ws;
  f16*   dense_h = (f16*)ws;
  float* s1      = (float*)(ws + (size_t)N * D * sizeof(f16));
  float* s2      = s1 + N;
  int*   row_ptr = (int*)(s2 + N);
  uintptr_t wtp  = (uintptr_t)(row_ptr + N + 1);
  wtp = (wtp + 15) & ~(uintptr_t)15;
  f16* wt = (f16*)wtp;

  wprep_kernel<<<(3 * 4096 + 255) / 256, 256, 0, stream>>>(Ww, W1w, W2w, wt);
  node_kernel<<<512, 256, 0, stream>>>(query, input_, wt, Wb, W1b,
                                       W2b, g1, b1, dense_h, s1, s2, N);
  rowptr_kernel<<<(E + 255) / 256, 256, 0, stream>>>(erow, row_ptr, E, N);
  const int waves = (N + 1) / 2;
  edge_kernel<<<(waves + 3) / 4, 256, 0, stream>>>(row_ptr, ecol, s1, s2,
                                                   dense_h, g2, b2, out, N);
}